// Round 5
// baseline (346.935 us; speedup 1.0000x reference)
//
#include <hip/hip_runtime.h>

#define H 64
#define G 64
#define OUT 2
#define TILE 1024

typedef unsigned int uint32;

__device__ inline float bf16lo(uint32 u) { return __uint_as_float(u << 16); }
__device__ inline float bf16hi(uint32 u) { return __uint_as_float(u & 0xffff0000u); }
__device__ inline uint32 packbf16(float a, float b) {
    uint32 ua = __float_as_uint(a);
    uint32 ub = __float_as_uint(b);
    ua = (ua + 0x7fffu + ((ua >> 16) & 1u)) >> 16;                 // RNE
    ub = (ub + 0x7fffu + ((ub >> 16) & 1u)) & 0xffff0000u;         // RNE
    return ua | ub;
}

// ---------------- zero ----------------
__global__ void k_zero_int(int* p, int n) {
    int i = blockIdx.x * blockDim.x + threadIdx.x;
    if (i < n) p[i] = 0;
}

__global__ void k_zero(float* p, int n) {
    int i = blockIdx.x * blockDim.x + threadIdx.x;
    if (i < n) p[i] = 0.0f;
}

// ---------------- in-degree histogram ----------------
__global__ void k_hist(const int* __restrict__ dst, int* __restrict__ counts, int e) {
    int i = blockIdx.x * blockDim.x + threadIdx.x;
    if (i < e) atomicAdd(&counts[dst[i]], 1);
}

// ---------------- 3-phase device-wide exclusive scan ----------------
__global__ __launch_bounds__(TILE) void k_scan1(const int* __restrict__ counts,
                                                int* __restrict__ rowptr,
                                                int* __restrict__ blocksums, int n) {
    __shared__ int sm[TILE];
    int t = threadIdx.x;
    int i = blockIdx.x * TILE + t;
    int v = (i < n) ? counts[i] : 0;
    sm[t] = v;
    __syncthreads();
    for (int off = 1; off < TILE; off <<= 1) {
        int u = (t >= off) ? sm[t - off] : 0;
        __syncthreads();
        sm[t] += u;
        __syncthreads();
    }
    if (i < n) rowptr[i] = sm[t] - v;  // exclusive
    if (t == TILE - 1) blocksums[blockIdx.x] = sm[t];
}

__global__ __launch_bounds__(256) void k_scan2(int* __restrict__ blocksums, int nb) {
    __shared__ int sm[256];
    int t = threadIdx.x;
    int v = (t < nb) ? blocksums[t] : 0;
    sm[t] = v;
    __syncthreads();
    for (int off = 1; off < 256; off <<= 1) {
        int u = (t >= off) ? sm[t - off] : 0;
        __syncthreads();
        sm[t] += u;
        __syncthreads();
    }
    if (t < nb) blocksums[t] = sm[t] - v;
}

__global__ __launch_bounds__(TILE) void k_scan3(const int* __restrict__ counts,
                                                int* __restrict__ rowptr,
                                                int* __restrict__ cursor,
                                                float* __restrict__ dinv,
                                                const int* __restrict__ blocksums,
                                                int n, int e_total) {
    int i = blockIdx.x * TILE + threadIdx.x;
    if (i < n) {
        int r = rowptr[i] + blocksums[blockIdx.x];
        rowptr[i] = r;
        cursor[i] = r;
        dinv[i] = rsqrtf((float)counts[i] + 1.0f);
    }
    if (i == 0) rowptr[n] = e_total;
}

// ---------------- fill CSR: csr[pos] = {src, norm} ----------------
__global__ void k_fill(const int* __restrict__ src, const int* __restrict__ dst,
                       const float* __restrict__ dinv, int* __restrict__ cursor,
                       int2* __restrict__ csr, int e) {
    int i = blockIdx.x * blockDim.x + threadIdx.x;
    if (i < e) {
        int s = src[i], d = dst[i];
        int pos = atomicAdd(&cursor[d], 1);
        float nrm = dinv[s] * dinv[d];
        csr[pos] = make_int2(s, __float_as_int(nrm));
    }
}

// ---------------- GEMM: Y(bf16)[n,64] = X[n,64] @ W[64,64] ----------------
// BFIN=0: X fp32; BFIN=1: X packed bf16. W held in 64 VGPRs/lane; X rows are
// wave-uniform -> scalar loads. Output packed bf16 (even lanes store pairs).
template <int BFIN>
__global__ __launch_bounds__(256) void k_gemm64(const void* __restrict__ Xv,
                                                const float* __restrict__ W,
                                                uint32* __restrict__ Y, int n) {
    int lane = threadIdx.x & 63;
    int wave = threadIdx.x >> 6;
    float wreg[64];
#pragma unroll
    for (int k = 0; k < 64; ++k) wreg[k] = W[k * 64 + lane];
    int base = blockIdx.x * 16 + wave * 4;
    if (base >= n) return;
    int r0 = min(base + 0, n - 1);
    int r1 = min(base + 1, n - 1);
    int r2 = min(base + 2, n - 1);
    int r3 = min(base + 3, n - 1);
    float a0 = 0.f, a1 = 0.f, a2 = 0.f, a3 = 0.f;
    if (BFIN) {
        const uint32* X = (const uint32*)Xv;
        const uint32* x0 = X + (size_t)r0 * 32;
        const uint32* x1 = X + (size_t)r1 * 32;
        const uint32* x2 = X + (size_t)r2 * 32;
        const uint32* x3 = X + (size_t)r3 * 32;
#pragma unroll
        for (int k = 0; k < 32; ++k) {
            uint32 u0 = x0[k], u1 = x1[k], u2 = x2[k], u3 = x3[k];
            float wl = wreg[2 * k], wh = wreg[2 * k + 1];
            a0 += bf16lo(u0) * wl + bf16hi(u0) * wh;
            a1 += bf16lo(u1) * wl + bf16hi(u1) * wh;
            a2 += bf16lo(u2) * wl + bf16hi(u2) * wh;
            a3 += bf16lo(u3) * wl + bf16hi(u3) * wh;
        }
    } else {
        const float* X = (const float*)Xv;
        const float* x0 = X + (size_t)r0 * 64;
        const float* x1 = X + (size_t)r1 * 64;
        const float* x2 = X + (size_t)r2 * 64;
        const float* x3 = X + (size_t)r3 * 64;
#pragma unroll
        for (int k = 0; k < 64; ++k) {
            float w = wreg[k];
            a0 += x0[k] * w;
            a1 += x1[k] * w;
            a2 += x2[k] * w;
            a3 += x3[k] * w;
        }
    }
    // pack pairs of channels: even lane packs (own, lane+1)
    float b0 = __shfl_xor(a0, 1);
    float b1 = __shfl_xor(a1, 1);
    float b2 = __shfl_xor(a2, 1);
    float b3 = __shfl_xor(a3, 1);
    if (!(lane & 1)) {
        int ci = lane >> 1;
        if (base + 0 < n) Y[(size_t)(base + 0) * 32 + ci] = packbf16(a0, b0);
        if (base + 1 < n) Y[(size_t)(base + 1) * 32 + ci] = packbf16(a1, b1);
        if (base + 2 < n) Y[(size_t)(base + 2) * 32 + ci] = packbf16(a2, b2);
        if (base + 3 < n) Y[(size_t)(base + 3) * 32 + ci] = packbf16(a3, b3);
    }
}

// ---------------- fused aggregate on packed bf16 ----------------
// one wave per dst node; lanes 0-31 handle even edges, 32-63 odd edges;
// each lane covers 2 channels (bf16x2). 4 edges in flight per iteration.
template <int DOPOOL>
__global__ __launch_bounds__(256) void k_aggregate(const uint32* __restrict__ h,
                                                   const int2* __restrict__ csr,
                                                   const int* __restrict__ rowptr,
                                                   const float* __restrict__ dinv,
                                                   const float* __restrict__ b,
                                                   const int* __restrict__ batch,
                                                   uint32* __restrict__ hout,
                                                   float* __restrict__ pooled, int n) {
    __shared__ float red[4][64];
    __shared__ int sg[4];
    int lane = threadIdx.x & 63;
    int wave = threadIdx.x >> 6;
    int half = lane >> 5;   // 0: even edges, 1: odd edges
    int hl = lane & 31;     // uint index within row (2 channels)
    int node = blockIdx.x * 4 + wave;
    bool active = node < n;
    float acc0 = 0.f, acc1 = 0.f;
    if (active) {
        float dd = dinv[node];
        uint32 sv = h[(size_t)node * 32 + hl];
        if (half == 0) {  // self-loop term counted once
            acc0 = bf16lo(sv) * dd * dd;
            acc1 = bf16hi(sv) * dd * dd;
        }
        int r0 = rowptr[node], r1 = rowptr[node + 1];
        int e = r0;
        for (; e + 4 <= r1; e += 4) {
            int2 p0 = csr[e + half];
            int2 p1 = csr[e + 2 + half];
            uint32 g0 = h[(size_t)p0.x * 32 + hl];
            uint32 g1 = h[(size_t)p1.x * 32 + hl];
            float n0 = __int_as_float(p0.y);
            float n1 = __int_as_float(p1.y);
            acc0 += bf16lo(g0) * n0;
            acc1 += bf16hi(g0) * n0;
            acc0 += bf16lo(g1) * n1;
            acc1 += bf16hi(g1) * n1;
        }
        int ep = e + half;
        if (ep < r1) {
            int2 p = csr[ep];
            uint32 g = h[(size_t)p.x * 32 + hl];
            float nn = __int_as_float(p.y);
            acc0 += bf16lo(g) * nn;
            acc1 += bf16hi(g) * nn;
        }
        ep += 2;
        if (ep < r1) {
            int2 p = csr[ep];
            uint32 g = h[(size_t)p.x * 32 + hl];
            float nn = __int_as_float(p.y);
            acc0 += bf16lo(g) * nn;
            acc1 += bf16hi(g) * nn;
        }
    }
    // combine the two edge-halves (wave-uniform control here)
    float o0 = acc0 + __shfl_xor(acc0, 32);
    float o1 = acc1 + __shfl_xor(acc1, 32);
    if (active) {
        o0 += b[2 * hl + 0];
        o1 += b[2 * hl + 1];
        o0 = o0 > 0.f ? o0 : 0.f;
        o1 = o1 > 0.f ? o1 : 0.f;
        if (!DOPOOL && half == 0)
            hout[(size_t)node * 32 + hl] = packbf16(o0, o1);
    }
    if (DOPOOL) {
        // lane contributes one channel: ch = 2*hl + half
        red[wave][2 * hl + half] = active ? (half ? o1 : o0) : 0.f;
        if (lane == 0) sg[wave] = active ? batch[node] : -1;
        __syncthreads();
        if (wave == 0) {
            float s = red[0][lane];
            int gcur = sg[0];
            for (int w = 1; w < 4; ++w) {
                int gw = sg[w];
                if (gw < 0) break;
                if (gw == gcur) {
                    s += red[w][lane];
                } else {
                    if (gcur >= 0) atomicAdd(&pooled[gcur * H + lane], s);
                    s = red[w][lane];
                    gcur = gw;
                }
            }
            if (gcur >= 0) atomicAdd(&pooled[gcur * H + lane], s);
        }
    }
}

// ---------------- final linear ----------------
__global__ void k_final(const float* __restrict__ pooled, const float* __restrict__ gf,
                        const float* __restrict__ Wlin, const float* __restrict__ blin,
                        float* __restrict__ out) {
    int t = threadIdx.x;
    if (t >= G * OUT) return;
    int g = t >> 1, o = t & 1;
    float acc = blin[o];
#pragma unroll
    for (int j = 0; j < 64; ++j) acc += pooled[g * H + j] * Wlin[j * OUT + o];
    acc += gf[g] * Wlin[64 * OUT + o];
    out[g * OUT + o] = acc;
}

extern "C" void kernel_launch(void* const* d_in, const int* in_sizes, int n_in,
                              void* d_out, int out_size, void* d_ws, size_t ws_size,
                              hipStream_t stream) {
    const float* x          = (const float*)d_in[0];
    const int*   edge_index = (const int*)d_in[1];
    const int*   batch      = (const int*)d_in[2];
    const float* gf         = (const float*)d_in[3];
    const float* W1         = (const float*)d_in[4];
    const float* b1         = (const float*)d_in[5];
    const float* W2         = (const float*)d_in[6];
    const float* b2         = (const float*)d_in[7];
    const float* Wlin       = (const float*)d_in[8];
    const float* blin       = (const float*)d_in[9];
    float* out = (float*)d_out;

    const int N = in_sizes[0] / H;
    const int E = in_sizes[1] / 2;
    const int* src = edge_index;
    const int* dst = edge_index + E;

    // workspace layout (keep float-sized slots; bf16 buffers use half of them)
    float* ws = (float*)d_ws;
    float* dinv   = ws;                         // N
    uint32* bufA  = (uint32*)(dinv + N);        // N*32 uints (bf16 packed)
    uint32* bufB  = bufA + (size_t)N * 32;      // N*32 uints
    float* pooled = (float*)(bufB + (size_t)N * 32);  // G*H
    int*   counts = (int*)(pooled + G * H);     // N
    int*   rowptr = counts + N;                 // N+1
    int*   cursor = rowptr + (N + 1);           // N
    int*   blocksums = cursor + N;              // up to 256
    size_t off = (size_t)(blocksums + 256 - (int*)d_ws);
    off = (off + 1) & ~(size_t)1;
    int2*  csr    = (int2*)((int*)d_ws + off);  // E int2

    const int T = 256;
    const int NB = (N + TILE - 1) / TILE;       // <=256 required

    // CSR build (also produces dinv from in-degree+1)
    k_zero_int<<<(N + T - 1) / T, T, 0, stream>>>(counts, N);
    k_hist<<<(E + T - 1) / T, T, 0, stream>>>(dst, counts, E);
    k_scan1<<<NB, TILE, 0, stream>>>(counts, rowptr, blocksums, N);
    k_scan2<<<1, 256, 0, stream>>>(blocksums, NB);
    k_scan3<<<NB, TILE, 0, stream>>>(counts, rowptr, cursor, dinv, blocksums, N, E);
    k_fill<<<(E + T - 1) / T, T, 0, stream>>>(src, dst, dinv, cursor, csr, E);

    // zero pooled (poisoned by harness)
    k_zero<<<(G * H + T - 1) / T, T, 0, stream>>>(pooled, G * H);

    // layer 1: A1 = x@W1 (bf16), h1 = relu(agg(A1)+b1) (bf16)
    k_gemm64<0><<<(N + 15) / 16, T, 0, stream>>>(x, W1, bufA, N);
    k_aggregate<0><<<(N + 3) / 4, T, 0, stream>>>(bufA, csr, rowptr, dinv, b1, batch,
                                                  bufB, pooled, N);

    // layer 2 + fused pool: A2 = h1@W2 (bf16), pooled += relu(agg(A2)+b2)
    k_gemm64<1><<<(N + 15) / 16, T, 0, stream>>>(bufB, W2, bufA, N);
    k_aggregate<1><<<(N + 3) / 4, T, 0, stream>>>(bufA, csr, rowptr, dinv, b2, batch,
                                                  nullptr, pooled, N);

    // head
    k_final<<<1, 128, 0, stream>>>(pooled, gf, Wlin, blin, out);
}

// Round 6
// 335.229 us; speedup vs baseline: 1.0349x; 1.0349x over previous
//
#include <hip/hip_runtime.h>

#define H 64
#define G 64
#define OUT 2
#define TILE 1024

typedef unsigned int uint32;

__device__ inline float bf16lo(uint32 u) { return __uint_as_float(u << 16); }
__device__ inline float bf16hi(uint32 u) { return __uint_as_float(u & 0xffff0000u); }
__device__ inline uint32 packbf16(float a, float b) {
    uint32 ua = __float_as_uint(a);
    uint32 ub = __float_as_uint(b);
    ua = (ua + 0x7fffu + ((ua >> 16) & 1u)) >> 16;                 // RNE
    ub = (ub + 0x7fffu + ((ub >> 16) & 1u)) & 0xffff0000u;         // RNE
    return ua | ub;
}

// ---------------- zero ----------------
__global__ void k_zero_int(int* p, int n) {
    int i = blockIdx.x * blockDim.x + threadIdx.x;
    if (i < n) p[i] = 0;
}

__global__ void k_zero(float* p, int n) {
    int i = blockIdx.x * blockDim.x + threadIdx.x;
    if (i < n) p[i] = 0.0f;
}

// ---------------- in-degree histogram ----------------
__global__ void k_hist(const int* __restrict__ dst, int* __restrict__ counts, int e) {
    int i = blockIdx.x * blockDim.x + threadIdx.x;
    if (i < e) atomicAdd(&counts[dst[i]], 1);
}

// ---------------- 3-phase device-wide exclusive scan ----------------
__global__ __launch_bounds__(TILE) void k_scan1(const int* __restrict__ counts,
                                                int* __restrict__ rowptr,
                                                int* __restrict__ blocksums, int n) {
    __shared__ int sm[TILE];
    int t = threadIdx.x;
    int i = blockIdx.x * TILE + t;
    int v = (i < n) ? counts[i] : 0;
    sm[t] = v;
    __syncthreads();
    for (int off = 1; off < TILE; off <<= 1) {
        int u = (t >= off) ? sm[t - off] : 0;
        __syncthreads();
        sm[t] += u;
        __syncthreads();
    }
    if (i < n) rowptr[i] = sm[t] - v;  // exclusive
    if (t == TILE - 1) blocksums[blockIdx.x] = sm[t];
}

__global__ __launch_bounds__(256) void k_scan2(int* __restrict__ blocksums, int nb) {
    __shared__ int sm[256];
    int t = threadIdx.x;
    int v = (t < nb) ? blocksums[t] : 0;
    sm[t] = v;
    __syncthreads();
    for (int off = 1; off < 256; off <<= 1) {
        int u = (t >= off) ? sm[t - off] : 0;
        __syncthreads();
        sm[t] += u;
        __syncthreads();
    }
    if (t < nb) blocksums[t] = sm[t] - v;
}

__global__ __launch_bounds__(TILE) void k_scan3(const int* __restrict__ counts,
                                                int* __restrict__ rowptr,
                                                int* __restrict__ cursor,
                                                float* __restrict__ dinv,
                                                const int* __restrict__ blocksums,
                                                int n, int e_total) {
    int i = blockIdx.x * TILE + threadIdx.x;
    if (i < n) {
        int r = rowptr[i] + blocksums[blockIdx.x];
        rowptr[i] = r;
        cursor[i] = r;
        dinv[i] = rsqrtf((float)counts[i] + 1.0f);
    }
    if (i == 0) rowptr[n] = e_total;
}

// ---------------- fill CSR: csr[pos] = {src, norm} ----------------
__global__ void k_fill(const int* __restrict__ src, const int* __restrict__ dst,
                       const float* __restrict__ dinv, int* __restrict__ cursor,
                       int2* __restrict__ csr, int e) {
    int i = blockIdx.x * blockDim.x + threadIdx.x;
    if (i < e) {
        int s = src[i], d = dst[i];
        int pos = atomicAdd(&cursor[d], 1);
        float nrm = dinv[s] * dinv[d];
        csr[pos] = make_int2(s, __float_as_int(nrm));
    }
}

// ---------------- GEMM: Y(bf16)[n,64] = X[n,64] @ W[64,64] ----------------
template <int BFIN>
__global__ __launch_bounds__(256) void k_gemm64(const void* __restrict__ Xv,
                                                const float* __restrict__ W,
                                                uint32* __restrict__ Y, int n) {
    int lane = threadIdx.x & 63;
    int wave = threadIdx.x >> 6;
    float wreg[64];
#pragma unroll
    for (int k = 0; k < 64; ++k) wreg[k] = W[k * 64 + lane];
    int base = blockIdx.x * 16 + wave * 4;
    if (base >= n) return;
    int r0 = min(base + 0, n - 1);
    int r1 = min(base + 1, n - 1);
    int r2 = min(base + 2, n - 1);
    int r3 = min(base + 3, n - 1);
    float a0 = 0.f, a1 = 0.f, a2 = 0.f, a3 = 0.f;
    if (BFIN) {
        const uint32* X = (const uint32*)Xv;
        const uint32* x0 = X + (size_t)r0 * 32;
        const uint32* x1 = X + (size_t)r1 * 32;
        const uint32* x2 = X + (size_t)r2 * 32;
        const uint32* x3 = X + (size_t)r3 * 32;
#pragma unroll
        for (int k = 0; k < 32; ++k) {
            uint32 u0 = x0[k], u1 = x1[k], u2 = x2[k], u3 = x3[k];
            float wl = wreg[2 * k], wh = wreg[2 * k + 1];
            a0 += bf16lo(u0) * wl + bf16hi(u0) * wh;
            a1 += bf16lo(u1) * wl + bf16hi(u1) * wh;
            a2 += bf16lo(u2) * wl + bf16hi(u2) * wh;
            a3 += bf16lo(u3) * wl + bf16hi(u3) * wh;
        }
    } else {
        const float* X = (const float*)Xv;
        const float* x0 = X + (size_t)r0 * 64;
        const float* x1 = X + (size_t)r1 * 64;
        const float* x2 = X + (size_t)r2 * 64;
        const float* x3 = X + (size_t)r3 * 64;
#pragma unroll
        for (int k = 0; k < 64; ++k) {
            float w = wreg[k];
            a0 += x0[k] * w;
            a1 += x1[k] * w;
            a2 += x2[k] * w;
            a3 += x3[k] * w;
        }
    }
    // pack pairs of channels: even lane packs (own, lane+1)
    float b0 = __shfl_xor(a0, 1);
    float b1 = __shfl_xor(a1, 1);
    float b2 = __shfl_xor(a2, 1);
    float b3 = __shfl_xor(a3, 1);
    if (!(lane & 1)) {
        int ci = lane >> 1;
        if (base + 0 < n) Y[(size_t)(base + 0) * 32 + ci] = packbf16(a0, b0);
        if (base + 1 < n) Y[(size_t)(base + 1) * 32 + ci] = packbf16(a1, b1);
        if (base + 2 < n) Y[(size_t)(base + 2) * 32 + ci] = packbf16(a2, b2);
        if (base + 3 < n) Y[(size_t)(base + 3) * 32 + ci] = packbf16(a3, b3);
    }
}

// ---------------- fused aggregate on packed bf16 ----------------
// one wave per dst node; lanes 0-31 handle even edges, 32-63 odd edges;
// each lane covers 2 channels (bf16x2). 8 edges / 4 gathers in flight per iter.
template <int DOPOOL>
__global__ __launch_bounds__(256) void k_aggregate(const uint32* __restrict__ h,
                                                   const int2* __restrict__ csr,
                                                   const int* __restrict__ rowptr,
                                                   const float* __restrict__ dinv,
                                                   const float* __restrict__ b,
                                                   const int* __restrict__ batch,
                                                   uint32* __restrict__ hout,
                                                   float* __restrict__ pooled, int n) {
    __shared__ float red[4][64];
    __shared__ int sg[4];
    int lane = threadIdx.x & 63;
    int wave = threadIdx.x >> 6;
    int half = lane >> 5;   // 0: even edges, 1: odd edges
    int hl = lane & 31;     // uint index within row (2 channels)
    int node = blockIdx.x * 4 + wave;
    bool active = node < n;
    float acc0 = 0.f, acc1 = 0.f;
    if (active) {
        float dd = dinv[node];
        uint32 sv = h[(size_t)node * 32 + hl];
        if (half == 0) {  // self-loop term counted once
            acc0 = bf16lo(sv) * dd * dd;
            acc1 = bf16hi(sv) * dd * dd;
        }
        int r0 = rowptr[node], r1 = rowptr[node + 1];
        int e = r0;
        // 8 edges per iteration: 4 independent gathers in flight per half
        for (; e + 8 <= r1; e += 8) {
            int2 p0 = csr[e + 0 + half];
            int2 p1 = csr[e + 2 + half];
            int2 p2 = csr[e + 4 + half];
            int2 p3 = csr[e + 6 + half];
            uint32 g0 = h[(size_t)p0.x * 32 + hl];
            uint32 g1 = h[(size_t)p1.x * 32 + hl];
            uint32 g2 = h[(size_t)p2.x * 32 + hl];
            uint32 g3 = h[(size_t)p3.x * 32 + hl];
            float n0 = __int_as_float(p0.y);
            float n1 = __int_as_float(p1.y);
            float n2 = __int_as_float(p2.y);
            float n3 = __int_as_float(p3.y);
            acc0 += bf16lo(g0) * n0;  acc1 += bf16hi(g0) * n0;
            acc0 += bf16lo(g1) * n1;  acc1 += bf16hi(g1) * n1;
            acc0 += bf16lo(g2) * n2;  acc1 += bf16hi(g2) * n2;
            acc0 += bf16lo(g3) * n3;  acc1 += bf16hi(g3) * n3;
        }
        for (; e + 4 <= r1; e += 4) {
            int2 p0 = csr[e + half];
            int2 p1 = csr[e + 2 + half];
            uint32 g0 = h[(size_t)p0.x * 32 + hl];
            uint32 g1 = h[(size_t)p1.x * 32 + hl];
            float n0 = __int_as_float(p0.y);
            float n1 = __int_as_float(p1.y);
            acc0 += bf16lo(g0) * n0;  acc1 += bf16hi(g0) * n0;
            acc0 += bf16lo(g1) * n1;  acc1 += bf16hi(g1) * n1;
        }
        int ep = e + half;
        if (ep < r1) {
            int2 p = csr[ep];
            uint32 g = h[(size_t)p.x * 32 + hl];
            float nn = __int_as_float(p.y);
            acc0 += bf16lo(g) * nn;
            acc1 += bf16hi(g) * nn;
        }
        ep += 2;
        if (ep < r1) {
            int2 p = csr[ep];
            uint32 g = h[(size_t)p.x * 32 + hl];
            float nn = __int_as_float(p.y);
            acc0 += bf16lo(g) * nn;
            acc1 += bf16hi(g) * nn;
        }
    }
    // combine the two edge-halves (wave-uniform control here)
    float o0 = acc0 + __shfl_xor(acc0, 32);
    float o1 = acc1 + __shfl_xor(acc1, 32);
    if (active) {
        o0 += b[2 * hl + 0];
        o1 += b[2 * hl + 1];
        o0 = o0 > 0.f ? o0 : 0.f;
        o1 = o1 > 0.f ? o1 : 0.f;
        if (!DOPOOL && half == 0)
            hout[(size_t)node * 32 + hl] = packbf16(o0, o1);
    }
    if (DOPOOL) {
        red[wave][2 * hl + half] = active ? (half ? o1 : o0) : 0.f;
        if (lane == 0) sg[wave] = active ? batch[node] : -1;
        __syncthreads();
        if (wave == 0) {
            float s = red[0][lane];
            int gcur = sg[0];
            for (int w = 1; w < 4; ++w) {
                int gw = sg[w];
                if (gw < 0) break;
                if (gw == gcur) {
                    s += red[w][lane];
                } else {
                    if (gcur >= 0) atomicAdd(&pooled[gcur * H + lane], s);
                    s = red[w][lane];
                    gcur = gw;
                }
            }
            if (gcur >= 0) atomicAdd(&pooled[gcur * H + lane], s);
        }
    }
}

// ---------------- final linear ----------------
__global__ void k_final(const float* __restrict__ pooled, const float* __restrict__ gf,
                        const float* __restrict__ Wlin, const float* __restrict__ blin,
                        float* __restrict__ out) {
    int t = threadIdx.x;
    if (t >= G * OUT) return;
    int g = t >> 1, o = t & 1;
    float acc = blin[o];
#pragma unroll
    for (int j = 0; j < 64; ++j) acc += pooled[g * H + j] * Wlin[j * OUT + o];
    acc += gf[g] * Wlin[64 * OUT + o];
    out[g * OUT + o] = acc;
}

extern "C" void kernel_launch(void* const* d_in, const int* in_sizes, int n_in,
                              void* d_out, int out_size, void* d_ws, size_t ws_size,
                              hipStream_t stream) {
    const float* x          = (const float*)d_in[0];
    const int*   edge_index = (const int*)d_in[1];
    const int*   batch      = (const int*)d_in[2];
    const float* gf         = (const float*)d_in[3];
    const float* W1         = (const float*)d_in[4];
    const float* b1         = (const float*)d_in[5];
    const float* W2         = (const float*)d_in[6];
    const float* b2         = (const float*)d_in[7];
    const float* Wlin       = (const float*)d_in[8];
    const float* blin       = (const float*)d_in[9];
    float* out = (float*)d_out;

    const int N = in_sizes[0] / H;
    const int E = in_sizes[1] / 2;
    const int* src = edge_index;
    const int* dst = edge_index + E;

    // workspace layout
    float* ws = (float*)d_ws;
    float* dinv   = ws;                         // N
    uint32* bufA  = (uint32*)(dinv + N);        // N*32 uints (bf16 packed)
    uint32* bufB  = bufA + (size_t)N * 32;      // N*32 uints
    float* pooled = (float*)(bufB + (size_t)N * 32);  // G*H
    int*   counts = (int*)(pooled + G * H);     // N
    int*   rowptr = counts + N;                 // N+1
    int*   cursor = rowptr + (N + 1);           // N
    int*   blocksums = cursor + N;              // up to 256
    size_t off = (size_t)(blocksums + 256 - (int*)d_ws);
    off = (off + 1) & ~(size_t)1;
    int2*  csr    = (int2*)((int*)d_ws + off);  // E int2

    const int T = 256;
    const int NB = (N + TILE - 1) / TILE;       // <=256 required

    // CSR build (also produces dinv from in-degree+1)
    k_zero_int<<<(N + T - 1) / T, T, 0, stream>>>(counts, N);
    k_hist<<<(E + T - 1) / T, T, 0, stream>>>(dst, counts, E);
    k_scan1<<<NB, TILE, 0, stream>>>(counts, rowptr, blocksums, N);
    k_scan2<<<1, 256, 0, stream>>>(blocksums, NB);
    k_scan3<<<NB, TILE, 0, stream>>>(counts, rowptr, cursor, dinv, blocksums, N, E);
    k_fill<<<(E + T - 1) / T, T, 0, stream>>>(src, dst, dinv, cursor, csr, E);

    // zero pooled (poisoned by harness)
    k_zero<<<(G * H + T - 1) / T, T, 0, stream>>>(pooled, G * H);

    // layer 1: A1 = x@W1 (bf16), h1 = relu(agg(A1)+b1) (bf16)
    k_gemm64<0><<<(N + 15) / 16, T, 0, stream>>>(x, W1, bufA, N);
    k_aggregate<0><<<(N + 3) / 4, T, 0, stream>>>(bufA, csr, rowptr, dinv, b1, batch,
                                                  bufB, pooled, N);

    // layer 2 + fused pool
    k_gemm64<1><<<(N + 15) / 16, T, 0, stream>>>(bufB, W2, bufA, N);
    k_aggregate<1><<<(N + 3) / 4, T, 0, stream>>>(bufA, csr, rowptr, dinv, b2, batch,
                                                  nullptr, pooled, N);

    // head
    k_final<<<1, 128, 0, stream>>>(pooled, gf, Wlin, blin, out);
}

// Round 7
// 294.486 us; speedup vs baseline: 1.1781x; 1.1384x over previous
//
#include <hip/hip_runtime.h>

#define H 64
#define G 64
#define OUT 2
#define TILE 1024

typedef unsigned int uint32;

__device__ inline float bf16lo(uint32 u) { return __uint_as_float(u << 16); }
__device__ inline float bf16hi(uint32 u) { return __uint_as_float(u & 0xffff0000u); }
__device__ inline uint32 packbf16(float a, float b) {
    uint32 ua = __float_as_uint(a);
    uint32 ub = __float_as_uint(b);
    ua = (ua + 0x7fffu + ((ua >> 16) & 1u)) >> 16;                 // RNE
    ub = (ub + 0x7fffu + ((ub >> 16) & 1u)) & 0xffff0000u;         // RNE
    return ua | ub;
}

// ---------------- zero ----------------
__global__ void k_zero_int(int* p, int n) {
    int i = blockIdx.x * blockDim.x + threadIdx.x;
    if (i < n) p[i] = 0;
}

__global__ void k_zero(float* p, int n) {
    int i = blockIdx.x * blockDim.x + threadIdx.x;
    if (i < n) p[i] = 0.0f;
}

// ---------------- in-degree histogram ----------------
__global__ void k_hist(const int* __restrict__ dst, int* __restrict__ counts, int e) {
    int i = blockIdx.x * blockDim.x + threadIdx.x;
    if (i < e) atomicAdd(&counts[dst[i]], 1);
}

// ---------------- 3-phase device-wide exclusive scan ----------------
__global__ __launch_bounds__(TILE) void k_scan1(const int* __restrict__ counts,
                                                int* __restrict__ rowptr,
                                                int* __restrict__ blocksums, int n) {
    __shared__ int sm[TILE];
    int t = threadIdx.x;
    int i = blockIdx.x * TILE + t;
    int v = (i < n) ? counts[i] : 0;
    sm[t] = v;
    __syncthreads();
    for (int off = 1; off < TILE; off <<= 1) {
        int u = (t >= off) ? sm[t - off] : 0;
        __syncthreads();
        sm[t] += u;
        __syncthreads();
    }
    if (i < n) rowptr[i] = sm[t] - v;  // exclusive
    if (t == TILE - 1) blocksums[blockIdx.x] = sm[t];
}

__global__ __launch_bounds__(256) void k_scan2(int* __restrict__ blocksums, int nb) {
    __shared__ int sm[256];
    int t = threadIdx.x;
    int v = (t < nb) ? blocksums[t] : 0;
    sm[t] = v;
    __syncthreads();
    for (int off = 1; off < 256; off <<= 1) {
        int u = (t >= off) ? sm[t - off] : 0;
        __syncthreads();
        sm[t] += u;
        __syncthreads();
    }
    if (t < nb) blocksums[t] = sm[t] - v;
}

__global__ __launch_bounds__(TILE) void k_scan3(const int* __restrict__ counts,
                                                int* __restrict__ rowptr,
                                                int* __restrict__ cursor,
                                                float* __restrict__ dinv,
                                                const int* __restrict__ blocksums,
                                                int n, int e_total) {
    int i = blockIdx.x * TILE + threadIdx.x;
    if (i < n) {
        int r = rowptr[i] + blocksums[blockIdx.x];
        rowptr[i] = r;
        cursor[i] = r;
        dinv[i] = rsqrtf((float)counts[i] + 1.0f);
    }
    if (i == 0) rowptr[n] = e_total;
}

// ---------------- fill CSR: csr[pos] = {src, norm} ----------------
__global__ void k_fill(const int* __restrict__ src, const int* __restrict__ dst,
                       const float* __restrict__ dinv, int* __restrict__ cursor,
                       int2* __restrict__ csr, int e) {
    int i = blockIdx.x * blockDim.x + threadIdx.x;
    if (i < e) {
        int s = src[i], d = dst[i];
        int pos = atomicAdd(&cursor[d], 1);
        float nrm = dinv[s] * dinv[d];
        csr[pos] = make_int2(s, __float_as_int(nrm));
    }
}

// ---------------- GEMM: Y(bf16)[n,64] = X[n,64] @ W[64,64] ----------------
template <int BFIN>
__global__ __launch_bounds__(256) void k_gemm64(const void* __restrict__ Xv,
                                                const float* __restrict__ W,
                                                uint32* __restrict__ Y, int n) {
    int lane = threadIdx.x & 63;
    int wave = threadIdx.x >> 6;
    float wreg[64];
#pragma unroll
    for (int k = 0; k < 64; ++k) wreg[k] = W[k * 64 + lane];
    int base = blockIdx.x * 16 + wave * 4;
    if (base >= n) return;
    int r0 = min(base + 0, n - 1);
    int r1 = min(base + 1, n - 1);
    int r2 = min(base + 2, n - 1);
    int r3 = min(base + 3, n - 1);
    float a0 = 0.f, a1 = 0.f, a2 = 0.f, a3 = 0.f;
    if (BFIN) {
        const uint32* X = (const uint32*)Xv;
        const uint32* x0 = X + (size_t)r0 * 32;
        const uint32* x1 = X + (size_t)r1 * 32;
        const uint32* x2 = X + (size_t)r2 * 32;
        const uint32* x3 = X + (size_t)r3 * 32;
#pragma unroll
        for (int k = 0; k < 32; ++k) {
            uint32 u0 = x0[k], u1 = x1[k], u2 = x2[k], u3 = x3[k];
            float wl = wreg[2 * k], wh = wreg[2 * k + 1];
            a0 += bf16lo(u0) * wl + bf16hi(u0) * wh;
            a1 += bf16lo(u1) * wl + bf16hi(u1) * wh;
            a2 += bf16lo(u2) * wl + bf16hi(u2) * wh;
            a3 += bf16lo(u3) * wl + bf16hi(u3) * wh;
        }
    } else {
        const float* X = (const float*)Xv;
        const float* x0 = X + (size_t)r0 * 64;
        const float* x1 = X + (size_t)r1 * 64;
        const float* x2 = X + (size_t)r2 * 64;
        const float* x3 = X + (size_t)r3 * 64;
#pragma unroll
        for (int k = 0; k < 64; ++k) {
            float w = wreg[k];
            a0 += x0[k] * w;
            a1 += x1[k] * w;
            a2 += x2[k] * w;
            a3 += x3[k] * w;
        }
    }
    // pack pairs of channels: even lane packs (own, lane+1)
    float b0 = __shfl_xor(a0, 1);
    float b1 = __shfl_xor(a1, 1);
    float b2 = __shfl_xor(a2, 1);
    float b3 = __shfl_xor(a3, 1);
    if (!(lane & 1)) {
        int ci = lane >> 1;
        if (base + 0 < n) Y[(size_t)(base + 0) * 32 + ci] = packbf16(a0, b0);
        if (base + 1 < n) Y[(size_t)(base + 1) * 32 + ci] = packbf16(a1, b1);
        if (base + 2 < n) Y[(size_t)(base + 2) * 32 + ci] = packbf16(a2, b2);
        if (base + 3 < n) Y[(size_t)(base + 3) * 32 + ci] = packbf16(a3, b3);
    }
}

// ---------------- fused aggregate on packed bf16 ----------------
// one node per HALF-wave (2 independent chains per wave, 8 nodes per block);
// branch-free clamped unroll-4: 4 gathers always in flight per half-wave.
template <int DOPOOL>
__global__ __launch_bounds__(256) void k_aggregate(const uint32* __restrict__ h,
                                                   const int2* __restrict__ csr,
                                                   const int* __restrict__ rowptr,
                                                   const float* __restrict__ dinv,
                                                   const float* __restrict__ b,
                                                   const int* __restrict__ batch,
                                                   uint32* __restrict__ hout,
                                                   float* __restrict__ pooled, int n) {
    __shared__ float red[8][64];
    __shared__ int sg[8];
    int tid = threadIdx.x;
    int wave = tid >> 6;
    int lane = tid & 63;
    int half = lane >> 5;          // which node of this wave's pair
    int hl = lane & 31;            // uint index within the 32-uint row
    int slot = wave * 2 + half;    // node slot within block (0..7)
    int node = blockIdx.x * 8 + slot;
    bool active = node < n;
    float o0 = 0.f, o1 = 0.f;
    if (active) {
        int r0 = rowptr[node];
        int r1 = rowptr[node + 1];
        float dd = dinv[node];
        uint32 sv = h[(size_t)node * 32 + hl];
        float acc0 = bf16lo(sv) * (dd * dd);
        float acc1 = bf16hi(sv) * (dd * dd);
        int m = r1 - 1;
        for (int e = r0; e < r1; e += 4) {
            int e1 = min(e + 1, m);
            int e2 = min(e + 2, m);
            int e3 = min(e + 3, m);
            int2 p0 = csr[e];
            int2 p1 = csr[e1];
            int2 p2 = csr[e2];
            int2 p3 = csr[e3];
            uint32 g0 = h[(size_t)p0.x * 32 + hl];
            uint32 g1 = h[(size_t)p1.x * 32 + hl];
            uint32 g2 = h[(size_t)p2.x * 32 + hl];
            uint32 g3 = h[(size_t)p3.x * 32 + hl];
            float n0 = __int_as_float(p0.y);
            float n1 = (e + 1 <= m) ? __int_as_float(p1.y) : 0.f;
            float n2 = (e + 2 <= m) ? __int_as_float(p2.y) : 0.f;
            float n3 = (e + 3 <= m) ? __int_as_float(p3.y) : 0.f;
            acc0 += bf16lo(g0) * n0;  acc1 += bf16hi(g0) * n0;
            acc0 += bf16lo(g1) * n1;  acc1 += bf16hi(g1) * n1;
            acc0 += bf16lo(g2) * n2;  acc1 += bf16hi(g2) * n2;
            acc0 += bf16lo(g3) * n3;  acc1 += bf16hi(g3) * n3;
        }
        o0 = acc0 + b[2 * hl + 0];
        o1 = acc1 + b[2 * hl + 1];
        o0 = o0 > 0.f ? o0 : 0.f;
        o1 = o1 > 0.f ? o1 : 0.f;
        if (!DOPOOL) hout[(size_t)node * 32 + hl] = packbf16(o0, o1);
    }
    if (DOPOOL) {
        red[slot][2 * hl + 0] = active ? o0 : 0.f;
        red[slot][2 * hl + 1] = active ? o1 : 0.f;
        if (hl == 0) sg[slot] = active ? batch[node] : -1;
        __syncthreads();
        if (wave == 0) {
            // merge runs of equal graph id (batch sorted) -> fewer atomics
            float s = red[0][lane];
            int gcur = sg[0];
            for (int w = 1; w < 8; ++w) {
                int gw = sg[w];
                if (gw < 0) break;
                if (gw == gcur) {
                    s += red[w][lane];
                } else {
                    if (gcur >= 0) atomicAdd(&pooled[gcur * H + lane], s);
                    s = red[w][lane];
                    gcur = gw;
                }
            }
            if (gcur >= 0) atomicAdd(&pooled[gcur * H + lane], s);
        }
    }
}

// ---------------- final linear ----------------
__global__ void k_final(const float* __restrict__ pooled, const float* __restrict__ gf,
                        const float* __restrict__ Wlin, const float* __restrict__ blin,
                        float* __restrict__ out) {
    int t = threadIdx.x;
    if (t >= G * OUT) return;
    int g = t >> 1, o = t & 1;
    float acc = blin[o];
#pragma unroll
    for (int j = 0; j < 64; ++j) acc += pooled[g * H + j] * Wlin[j * OUT + o];
    acc += gf[g] * Wlin[64 * OUT + o];
    out[g * OUT + o] = acc;
}

extern "C" void kernel_launch(void* const* d_in, const int* in_sizes, int n_in,
                              void* d_out, int out_size, void* d_ws, size_t ws_size,
                              hipStream_t stream) {
    const float* x          = (const float*)d_in[0];
    const int*   edge_index = (const int*)d_in[1];
    const int*   batch      = (const int*)d_in[2];
    const float* gf         = (const float*)d_in[3];
    const float* W1         = (const float*)d_in[4];
    const float* b1         = (const float*)d_in[5];
    const float* W2         = (const float*)d_in[6];
    const float* b2         = (const float*)d_in[7];
    const float* Wlin       = (const float*)d_in[8];
    const float* blin       = (const float*)d_in[9];
    float* out = (float*)d_out;

    const int N = in_sizes[0] / H;
    const int E = in_sizes[1] / 2;
    const int* src = edge_index;
    const int* dst = edge_index + E;

    // workspace layout
    float* ws = (float*)d_ws;
    float* dinv   = ws;                         // N
    uint32* bufA  = (uint32*)(dinv + N);        // N*32 uints (bf16 packed)
    uint32* bufB  = bufA + (size_t)N * 32;      // N*32 uints
    float* pooled = (float*)(bufB + (size_t)N * 32);  // G*H
    int*   counts = (int*)(pooled + G * H);     // N
    int*   rowptr = counts + N;                 // N+1
    int*   cursor = rowptr + (N + 1);           // N
    int*   blocksums = cursor + N;              // up to 256
    size_t off = (size_t)(blocksums + 256 - (int*)d_ws);
    off = (off + 1) & ~(size_t)1;
    int2*  csr    = (int2*)((int*)d_ws + off);  // E int2

    const int T = 256;
    const int NB = (N + TILE - 1) / TILE;       // <=256 required

    // CSR build (also produces dinv from in-degree+1)
    k_zero_int<<<(N + T - 1) / T, T, 0, stream>>>(counts, N);
    k_hist<<<(E + T - 1) / T, T, 0, stream>>>(dst, counts, E);
    k_scan1<<<NB, TILE, 0, stream>>>(counts, rowptr, blocksums, N);
    k_scan2<<<1, 256, 0, stream>>>(blocksums, NB);
    k_scan3<<<NB, TILE, 0, stream>>>(counts, rowptr, cursor, dinv, blocksums, N, E);
    k_fill<<<(E + T - 1) / T, T, 0, stream>>>(src, dst, dinv, cursor, csr, E);

    // zero pooled (poisoned by harness)
    k_zero<<<(G * H + T - 1) / T, T, 0, stream>>>(pooled, G * H);

    // layer 1: A1 = x@W1 (bf16), h1 = relu(agg(A1)+b1) (bf16)
    k_gemm64<0><<<(N + 15) / 16, T, 0, stream>>>(x, W1, bufA, N);
    k_aggregate<0><<<(N + 7) / 8, T, 0, stream>>>(bufA, csr, rowptr, dinv, b1, batch,
                                                  bufB, pooled, N);

    // layer 2 + fused pool
    k_gemm64<1><<<(N + 15) / 16, T, 0, stream>>>(bufB, W2, bufA, N);
    k_aggregate<1><<<(N + 7) / 8, T, 0, stream>>>(bufA, csr, rowptr, dinv, b2, batch,
                                                  nullptr, pooled, N);

    // head
    k_final<<<1, 128, 0, stream>>>(pooled, gf, Wlin, blin, out);
}

// Round 8
// 231.264 us; speedup vs baseline: 1.5002x; 1.2734x over previous
//
#include <hip/hip_runtime.h>

#define H 64
#define G 64
#define OUT 2
#define TILE 1024

typedef unsigned int uint32;
using short8 = __attribute__((ext_vector_type(8))) short;
using f32x4  = __attribute__((ext_vector_type(4))) float;

union ABFrag { uint32 u[4]; uint4 q; short8 v; };

__device__ inline float bf16lo(uint32 u) { return __uint_as_float(u << 16); }
__device__ inline float bf16hi(uint32 u) { return __uint_as_float(u & 0xffff0000u); }
__device__ inline uint32 packbf16(float a, float b) {
    uint32 ua = __float_as_uint(a);
    uint32 ub = __float_as_uint(b);
    ua = (ua + 0x7fffu + ((ua >> 16) & 1u)) >> 16;                 // RNE
    ub = (ub + 0x7fffu + ((ub >> 16) & 1u)) & 0xffff0000u;         // RNE
    return ua | ub;
}

// ---------------- zero ----------------
__global__ void k_zero_int(int* p, int n) {
    int i = blockIdx.x * blockDim.x + threadIdx.x;
    if (i < n) p[i] = 0;
}

__global__ void k_zero(float* p, int n) {
    int i = blockIdx.x * blockDim.x + threadIdx.x;
    if (i < n) p[i] = 0.0f;
}

// ---------------- in-degree histogram ----------------
__global__ void k_hist(const int* __restrict__ dst, int* __restrict__ counts, int e) {
    int i = blockIdx.x * blockDim.x + threadIdx.x;
    if (i < e) atomicAdd(&counts[dst[i]], 1);
}

// ---------------- 3-phase device-wide exclusive scan ----------------
__global__ __launch_bounds__(TILE) void k_scan1(const int* __restrict__ counts,
                                                int* __restrict__ rowptr,
                                                int* __restrict__ blocksums, int n) {
    __shared__ int sm[TILE];
    int t = threadIdx.x;
    int i = blockIdx.x * TILE + t;
    int v = (i < n) ? counts[i] : 0;
    sm[t] = v;
    __syncthreads();
    for (int off = 1; off < TILE; off <<= 1) {
        int u = (t >= off) ? sm[t - off] : 0;
        __syncthreads();
        sm[t] += u;
        __syncthreads();
    }
    if (i < n) rowptr[i] = sm[t] - v;  // exclusive
    if (t == TILE - 1) blocksums[blockIdx.x] = sm[t];
}

__global__ __launch_bounds__(256) void k_scan2(int* __restrict__ blocksums, int nb) {
    __shared__ int sm[256];
    int t = threadIdx.x;
    int v = (t < nb) ? blocksums[t] : 0;
    sm[t] = v;
    __syncthreads();
    for (int off = 1; off < 256; off <<= 1) {
        int u = (t >= off) ? sm[t - off] : 0;
        __syncthreads();
        sm[t] += u;
        __syncthreads();
    }
    if (t < nb) blocksums[t] = sm[t] - v;
}

__global__ __launch_bounds__(TILE) void k_scan3(const int* __restrict__ counts,
                                                int* __restrict__ rowptr,
                                                int* __restrict__ cursor,
                                                float* __restrict__ dinv,
                                                const int* __restrict__ blocksums,
                                                int n, int e_total) {
    int i = blockIdx.x * TILE + threadIdx.x;
    if (i < n) {
        int r = rowptr[i] + blocksums[blockIdx.x];
        rowptr[i] = r;
        cursor[i] = r;
        dinv[i] = rsqrtf((float)counts[i] + 1.0f);
    }
    if (i == 0) rowptr[n] = e_total;
}

// ---------------- fill CSR: csrs[pos] = src  (norm folded into gemm epilogue) ----------------
__global__ void k_fill(const int* __restrict__ src, const int* __restrict__ dst,
                       int* __restrict__ cursor, int* __restrict__ csrs, int e) {
    int i = blockIdx.x * blockDim.x + threadIdx.x;
    if (i < e) {
        int d = dst[i];
        int pos = atomicAdd(&cursor[d], 1);
        csrs[pos] = src[i];
    }
}

// ---------------- pack W into MFMA B-fragment layout (bf16) ----------------
// B frag for 16x16x32: lane l holds B[k=(ks*32)+(l>>4)*8+j][col=ct*16+(l&15)], j=0..7
__global__ void k_prepW(const float* __restrict__ W, uint32* __restrict__ Wb) {
    int lane = threadIdx.x;  // 64 threads
    for (int ct = 0; ct < 4; ++ct)
        for (int ks = 0; ks < 2; ++ks) {
            int col = ct * 16 + (lane & 15);
            int k0 = ks * 32 + (lane >> 4) * 8;
            int slot = ct * 2 + ks;
            for (int r = 0; r < 4; ++r) {
                float a = W[(k0 + 2 * r) * 64 + col];
                float b = W[(k0 + 2 * r + 1) * 64 + col];
                Wb[(slot * 64 + lane) * 4 + r] = packbf16(a, b);
            }
        }
}

// ---------------- MFMA GEMM: Y(bf16,[n,64]) = (X[n,64] @ W) * dinv[row] ----------------
// wave = 32 rows x 64 cols; block = 4 waves = 128 rows
template <int BFIN>
__global__ __launch_bounds__(256) void k_gemm_mfma(const void* __restrict__ Xv,
                                                   const uint32* __restrict__ Wb,
                                                   const float* __restrict__ dinv,
                                                   uint32* __restrict__ Y, int n) {
    int lane = threadIdx.x & 63;
    int wave = threadIdx.x >> 6;
    int l15 = lane & 15;
    int grp = lane >> 4;  // 0..3
    // B frags (shared across all blocks -> L2-hot)
    ABFrag bf[4][2];
    const uint4* Wb4 = (const uint4*)Wb;
#pragma unroll
    for (int ct = 0; ct < 4; ++ct)
#pragma unroll
        for (int ks = 0; ks < 2; ++ks)
            bf[ct][ks].q = Wb4[(ct * 2 + ks) * 64 + lane];

    int rbase0 = blockIdx.x * 128 + wave * 32;
    f32x4 acc[2][4] = {};
#pragma unroll
    for (int sub = 0; sub < 2; ++sub) {
        int row = min(rbase0 + sub * 16 + l15, n - 1);
        ABFrag a[2];
        if (BFIN) {
            const uint4* X4 = (const uint4*)Xv;
#pragma unroll
            for (int ks = 0; ks < 2; ++ks)
                a[ks].q = X4[(size_t)row * 8 + ks * 4 + grp];
        } else {
            const float4* X4 = (const float4*)Xv;
#pragma unroll
            for (int ks = 0; ks < 2; ++ks) {
                float4 f0 = X4[(size_t)row * 16 + ks * 8 + grp * 2];
                float4 f1 = X4[(size_t)row * 16 + ks * 8 + grp * 2 + 1];
                a[ks].u[0] = packbf16(f0.x, f0.y);
                a[ks].u[1] = packbf16(f0.z, f0.w);
                a[ks].u[2] = packbf16(f1.x, f1.y);
                a[ks].u[3] = packbf16(f1.z, f1.w);
            }
        }
#pragma unroll
        for (int ct = 0; ct < 4; ++ct) {
            acc[sub][ct] = __builtin_amdgcn_mfma_f32_16x16x32_bf16(a[0].v, bf[ct][0].v,
                                                                   acc[sub][ct], 0, 0, 0);
            acc[sub][ct] = __builtin_amdgcn_mfma_f32_16x16x32_bf16(a[1].v, bf[ct][1].v,
                                                                   acc[sub][ct], 0, 0, 0);
        }
    }
    // epilogue: scale by dinv[row], pack bf16 channel-pairs, store
#pragma unroll
    for (int sub = 0; sub < 2; ++sub) {
        int rb = rbase0 + sub * 16;
#pragma unroll
        for (int r = 0; r < 4; ++r) {
            int row = rb + grp * 4 + r;   // D: row=(lane>>4)*4+r, col=ct*16+(lane&15)
            float dd = dinv[min(row, n - 1)];
#pragma unroll
            for (int ct = 0; ct < 4; ++ct) {
                float v = acc[sub][ct][r] * dd;
                float w = __shfl_xor(v, 1);
                if (!(lane & 1) && row < n)
                    Y[(size_t)row * 32 + ct * 8 + (l15 >> 1)] = packbf16(v, w);
            }
        }
    }
}

// ---------------- fused aggregate: out = relu(dinv_d*(hs_d + sum hs_src) + b) ----------------
// one node per HALF-wave; clamped unroll-4 -> 4 gathers in flight per chain
template <int DOPOOL>
__global__ __launch_bounds__(256) void k_aggregate(const uint32* __restrict__ h,
                                                   const int* __restrict__ csrs,
                                                   const int* __restrict__ rowptr,
                                                   const float* __restrict__ dinv,
                                                   const float* __restrict__ b,
                                                   const int* __restrict__ batch,
                                                   uint32* __restrict__ hout,
                                                   float* __restrict__ pooled, int n) {
    __shared__ float red[8][64];
    __shared__ int sg[8];
    int tid = threadIdx.x;
    int wave = tid >> 6;
    int lane = tid & 63;
    int half = lane >> 5;
    int hl = lane & 31;
    int slot = wave * 2 + half;
    int node = blockIdx.x * 8 + slot;
    bool active = node < n;
    float o0 = 0.f, o1 = 0.f;
    if (active) {
        int r0 = rowptr[node];
        int r1 = rowptr[node + 1];
        uint32 sv = h[(size_t)node * 32 + hl];
        float acc0 = bf16lo(sv);
        float acc1 = bf16hi(sv);
        int m = r1 - 1;
        for (int e = r0; e < r1; e += 4) {
            int e1 = min(e + 1, m);
            int e2 = min(e + 2, m);
            int e3 = min(e + 3, m);
            int s0 = csrs[e];
            int s1 = csrs[e1];
            int s2 = csrs[e2];
            int s3 = csrs[e3];
            uint32 g0 = h[(size_t)s0 * 32 + hl];
            uint32 g1 = h[(size_t)s1 * 32 + hl];
            uint32 g2 = h[(size_t)s2 * 32 + hl];
            uint32 g3 = h[(size_t)s3 * 32 + hl];
            if (e + 1 > m) g1 = 0u;
            if (e + 2 > m) g2 = 0u;
            if (e + 3 > m) g3 = 0u;
            acc0 += (bf16lo(g0) + bf16lo(g1)) + (bf16lo(g2) + bf16lo(g3));
            acc1 += (bf16hi(g0) + bf16hi(g1)) + (bf16hi(g2) + bf16hi(g3));
        }
        float dd = dinv[node];
        o0 = acc0 * dd + b[2 * hl + 0];
        o1 = acc1 * dd + b[2 * hl + 1];
        o0 = o0 > 0.f ? o0 : 0.f;
        o1 = o1 > 0.f ? o1 : 0.f;
        if (!DOPOOL) hout[(size_t)node * 32 + hl] = packbf16(o0, o1);
    }
    if (DOPOOL) {
        red[slot][2 * hl + 0] = active ? o0 : 0.f;
        red[slot][2 * hl + 1] = active ? o1 : 0.f;
        if (hl == 0) sg[slot] = active ? batch[node] : -1;
        __syncthreads();
        if (wave == 0) {
            // merge runs of equal graph id (batch sorted) -> fewer atomics
            float s = red[0][lane];
            int gcur = sg[0];
            for (int w = 1; w < 8; ++w) {
                int gw = sg[w];
                if (gw < 0) break;
                if (gw == gcur) {
                    s += red[w][lane];
                } else {
                    if (gcur >= 0) atomicAdd(&pooled[gcur * H + lane], s);
                    s = red[w][lane];
                    gcur = gw;
                }
            }
            if (gcur >= 0) atomicAdd(&pooled[gcur * H + lane], s);
        }
    }
}

// ---------------- final linear ----------------
__global__ void k_final(const float* __restrict__ pooled, const float* __restrict__ gf,
                        const float* __restrict__ Wlin, const float* __restrict__ blin,
                        float* __restrict__ out) {
    int t = threadIdx.x;
    if (t >= G * OUT) return;
    int g = t >> 1, o = t & 1;
    float acc = blin[o];
#pragma unroll
    for (int j = 0; j < 64; ++j) acc += pooled[g * H + j] * Wlin[j * OUT + o];
    acc += gf[g] * Wlin[64 * OUT + o];
    out[g * OUT + o] = acc;
}

extern "C" void kernel_launch(void* const* d_in, const int* in_sizes, int n_in,
                              void* d_out, int out_size, void* d_ws, size_t ws_size,
                              hipStream_t stream) {
    const float* x          = (const float*)d_in[0];
    const int*   edge_index = (const int*)d_in[1];
    const int*   batch      = (const int*)d_in[2];
    const float* gf         = (const float*)d_in[3];
    const float* W1         = (const float*)d_in[4];
    const float* b1         = (const float*)d_in[5];
    const float* W2         = (const float*)d_in[6];
    const float* b2         = (const float*)d_in[7];
    const float* Wlin       = (const float*)d_in[8];
    const float* blin       = (const float*)d_in[9];
    float* out = (float*)d_out;

    const int N = in_sizes[0] / H;
    const int E = in_sizes[1] / 2;
    const int* src = edge_index;
    const int* dst = edge_index + E;

    // workspace layout
    float* ws = (float*)d_ws;
    float* dinv   = ws;                         // N
    uint32* bufA  = (uint32*)(dinv + N);        // N*32 uints (bf16 packed)
    uint32* bufB  = bufA + (size_t)N * 32;      // N*32 uints
    float* pooled = (float*)(bufB + (size_t)N * 32);  // G*H
    int*   counts = (int*)(pooled + G * H);     // N
    int*   rowptr = counts + N;                 // N+1
    int*   cursor = rowptr + (N + 1);           // N
    int*   blocksums = cursor + N;              // 256
    size_t off = (size_t)(blocksums + 256 - (int*)d_ws);
    off = (off + 3) & ~(size_t)3;               // 16B align for uint4 loads
    uint32* Wb   = (uint32*)d_ws + off;         // 2 * 2048 uints (B-frags for W1,W2)
    int*   csrs  = (int*)(Wb + 2 * 2048);       // E ints

    const int T = 256;
    const int NB = (N + TILE - 1) / TILE;       // <=256 required

    // CSR build (also produces dinv from in-degree+1)
    k_zero_int<<<(N + T - 1) / T, T, 0, stream>>>(counts, N);
    k_hist<<<(E + T - 1) / T, T, 0, stream>>>(dst, counts, E);
    k_scan1<<<NB, TILE, 0, stream>>>(counts, rowptr, blocksums, N);
    k_scan2<<<1, 256, 0, stream>>>(blocksums, NB);
    k_scan3<<<NB, TILE, 0, stream>>>(counts, rowptr, cursor, dinv, blocksums, N, E);
    k_fill<<<(E + T - 1) / T, T, 0, stream>>>(src, dst, cursor, csrs, E);

    // weight packing + pooled zero
    k_prepW<<<1, 64, 0, stream>>>(W1, Wb);
    k_prepW<<<1, 64, 0, stream>>>(W2, Wb + 2048);
    k_zero<<<(G * H + T - 1) / T, T, 0, stream>>>(pooled, G * H);

    const int NBG = (N + 127) / 128;

    // layer 1: hs1 = (x@W1)*dinv (bf16), h1 = relu(dinv*(hs1_d + sum hs1_src) + b1)
    k_gemm_mfma<0><<<NBG, T, 0, stream>>>(x, Wb, dinv, bufA, N);
    k_aggregate<0><<<(N + 7) / 8, T, 0, stream>>>(bufA, csrs, rowptr, dinv, b1, batch,
                                                  bufB, pooled, N);

    // layer 2 + fused pool
    k_gemm_mfma<1><<<NBG, T, 0, stream>>>(bufB, Wb + 2048, dinv, bufA, N);
    k_aggregate<1><<<(N + 7) / 8, T, 0, stream>>>(bufA, csrs, rowptr, dinv, b2, batch,
                                                  nullptr, pooled, N);

    // head
    k_final<<<1, 128, 0, stream>>>(pooled, gf, Wlin, blin, out);
}

// Round 9
// 214.628 us; speedup vs baseline: 1.6164x; 1.0775x over previous
//
#include <hip/hip_runtime.h>

#define H 64
#define G 64
#define OUT 2
#define TILE 1024

typedef unsigned int uint32;
using short8 = __attribute__((ext_vector_type(8))) short;
using f32x4  = __attribute__((ext_vector_type(4))) float;

union ABFrag { uint32 u[4]; uint4 q; short8 v; };

__device__ inline float bf16lo(uint32 u) { return __uint_as_float(u << 16); }
__device__ inline float bf16hi(uint32 u) { return __uint_as_float(u & 0xffff0000u); }
__device__ inline uint32 packbf16(float a, float b) {
    uint32 ua = __float_as_uint(a);
    uint32 ub = __float_as_uint(b);
    ua = (ua + 0x7fffu + ((ua >> 16) & 1u)) >> 16;                 // RNE
    ub = (ub + 0x7fffu + ((ub >> 16) & 1u)) & 0xffff0000u;         // RNE
    return ua | ub;
}

// ---------------- zero ----------------
__global__ void k_zero_int(int* p, int n) {
    int i = blockIdx.x * blockDim.x + threadIdx.x;
    if (i < n) p[i] = 0;
}

__global__ void k_zero(float* p, int n) {
    int i = blockIdx.x * blockDim.x + threadIdx.x;
    if (i < n) p[i] = 0.0f;
}

// ---------------- XCD-partitioned in-degree histogram ----------------
// blockIdx%8 selects a node-range partition; assuming round-robin block->XCD
// dispatch, each XCD's atomics stay in its own L2 (no cross-XCD line ping-pong).
__global__ __launch_bounds__(256) void k_hist_part(const int* __restrict__ dst,
                                                   int* __restrict__ counts,
                                                   int e, int psize) {
    int part = blockIdx.x & 7;
    int blk  = blockIdx.x >> 3;
    int nblk = gridDim.x >> 3;
    int lo = part * psize, hi = lo + psize;
    int stride = nblk * 256;
    for (int i = blk * 256 + threadIdx.x; i < e; i += stride) {
        int d = dst[i];
        if (d >= lo && d < hi) atomicAdd(&counts[d], 1);
    }
}

// ---------------- 3-phase device-wide exclusive scan ----------------
__global__ __launch_bounds__(TILE) void k_scan1(const int* __restrict__ counts,
                                                int* __restrict__ rowptr,
                                                int* __restrict__ blocksums, int n) {
    __shared__ int sm[TILE];
    int t = threadIdx.x;
    int i = blockIdx.x * TILE + t;
    int v = (i < n) ? counts[i] : 0;
    sm[t] = v;
    __syncthreads();
    for (int off = 1; off < TILE; off <<= 1) {
        int u = (t >= off) ? sm[t - off] : 0;
        __syncthreads();
        sm[t] += u;
        __syncthreads();
    }
    if (i < n) rowptr[i] = sm[t] - v;  // exclusive
    if (t == TILE - 1) blocksums[blockIdx.x] = sm[t];
}

__global__ __launch_bounds__(256) void k_scan2(int* __restrict__ blocksums, int nb) {
    __shared__ int sm[256];
    int t = threadIdx.x;
    int v = (t < nb) ? blocksums[t] : 0;
    sm[t] = v;
    __syncthreads();
    for (int off = 1; off < 256; off <<= 1) {
        int u = (t >= off) ? sm[t - off] : 0;
        __syncthreads();
        sm[t] += u;
        __syncthreads();
    }
    if (t < nb) blocksums[t] = sm[t] - v;
}

__global__ __launch_bounds__(TILE) void k_scan3(const int* __restrict__ counts,
                                                int* __restrict__ rowptr,
                                                int* __restrict__ cursor,
                                                float* __restrict__ dinv,
                                                const int* __restrict__ blocksums,
                                                int n, int e_total) {
    int i = blockIdx.x * TILE + threadIdx.x;
    if (i < n) {
        int r = rowptr[i] + blocksums[blockIdx.x];
        rowptr[i] = r;
        cursor[i] = r;
        dinv[i] = rsqrtf((float)counts[i] + 1.0f);
    }
    if (i == 0) rowptr[n] = e_total;
}

// ---------------- XCD-partitioned CSR fill: csrs[pos] = src ----------------
// partition p's csr slice [rowptr[lo],rowptr[hi]) is ~E/8*4B -> L2-resident
__global__ __launch_bounds__(256) void k_fill_part(const int* __restrict__ src,
                                                   const int* __restrict__ dst,
                                                   int* __restrict__ cursor,
                                                   int* __restrict__ csrs,
                                                   int e, int psize) {
    int part = blockIdx.x & 7;
    int blk  = blockIdx.x >> 3;
    int nblk = gridDim.x >> 3;
    int lo = part * psize, hi = lo + psize;
    int stride = nblk * 256;
    for (int i = blk * 256 + threadIdx.x; i < e; i += stride) {
        int d = dst[i];
        if (d >= lo && d < hi) {
            int pos = atomicAdd(&cursor[d], 1);
            csrs[pos] = src[i];
        }
    }
}

// ---------------- pack W into MFMA B-fragment layout (bf16) ----------------
__global__ void k_prepW(const float* __restrict__ W, uint32* __restrict__ Wb) {
    int lane = threadIdx.x;  // 64 threads
    for (int ct = 0; ct < 4; ++ct)
        for (int ks = 0; ks < 2; ++ks) {
            int col = ct * 16 + (lane & 15);
            int k0 = ks * 32 + (lane >> 4) * 8;
            int slot = ct * 2 + ks;
            for (int r = 0; r < 4; ++r) {
                float a = W[(k0 + 2 * r) * 64 + col];
                float b = W[(k0 + 2 * r + 1) * 64 + col];
                Wb[(slot * 64 + lane) * 4 + r] = packbf16(a, b);
            }
        }
}

// ---------------- MFMA GEMM: Y(bf16,[n,64]) = (X[n,64] @ W) * dinv[row] ----------------
template <int BFIN>
__global__ __launch_bounds__(256) void k_gemm_mfma(const void* __restrict__ Xv,
                                                   const uint32* __restrict__ Wb,
                                                   const float* __restrict__ dinv,
                                                   uint32* __restrict__ Y, int n) {
    int lane = threadIdx.x & 63;
    int wave = threadIdx.x >> 6;
    int l15 = lane & 15;
    int grp = lane >> 4;  // 0..3
    ABFrag bf[4][2];
    const uint4* Wb4 = (const uint4*)Wb;
#pragma unroll
    for (int ct = 0; ct < 4; ++ct)
#pragma unroll
        for (int ks = 0; ks < 2; ++ks)
            bf[ct][ks].q = Wb4[(ct * 2 + ks) * 64 + lane];

    int rbase0 = blockIdx.x * 128 + wave * 32;
    f32x4 acc[2][4] = {};
#pragma unroll
    for (int sub = 0; sub < 2; ++sub) {
        int row = min(rbase0 + sub * 16 + l15, n - 1);
        ABFrag a[2];
        if (BFIN) {
            const uint4* X4 = (const uint4*)Xv;
#pragma unroll
            for (int ks = 0; ks < 2; ++ks)
                a[ks].q = X4[(size_t)row * 8 + ks * 4 + grp];
        } else {
            const float4* X4 = (const float4*)Xv;
#pragma unroll
            for (int ks = 0; ks < 2; ++ks) {
                float4 f0 = X4[(size_t)row * 16 + ks * 8 + grp * 2];
                float4 f1 = X4[(size_t)row * 16 + ks * 8 + grp * 2 + 1];
                a[ks].u[0] = packbf16(f0.x, f0.y);
                a[ks].u[1] = packbf16(f0.z, f0.w);
                a[ks].u[2] = packbf16(f1.x, f1.y);
                a[ks].u[3] = packbf16(f1.z, f1.w);
            }
        }
#pragma unroll
        for (int ct = 0; ct < 4; ++ct) {
            acc[sub][ct] = __builtin_amdgcn_mfma_f32_16x16x32_bf16(a[0].v, bf[ct][0].v,
                                                                   acc[sub][ct], 0, 0, 0);
            acc[sub][ct] = __builtin_amdgcn_mfma_f32_16x16x32_bf16(a[1].v, bf[ct][1].v,
                                                                   acc[sub][ct], 0, 0, 0);
        }
    }
#pragma unroll
    for (int sub = 0; sub < 2; ++sub) {
        int rb = rbase0 + sub * 16;
#pragma unroll
        for (int r = 0; r < 4; ++r) {
            int row = rb + grp * 4 + r;
            float dd = dinv[min(row, n - 1)];
#pragma unroll
            for (int ct = 0; ct < 4; ++ct) {
                float v = acc[sub][ct][r] * dd;
                float w = __shfl_xor(v, 1);
                if (!(lane & 1) && row < n)
                    Y[(size_t)row * 32 + ct * 8 + (l15 >> 1)] = packbf16(v, w);
            }
        }
    }
}

// ---------------- fused aggregate: out = relu(dinv_d*(hs_d + sum hs_src) + b) ----------------
template <int DOPOOL>
__global__ __launch_bounds__(256) void k_aggregate(const uint32* __restrict__ h,
                                                   const int* __restrict__ csrs,
                                                   const int* __restrict__ rowptr,
                                                   const float* __restrict__ dinv,
                                                   const float* __restrict__ b,
                                                   const int* __restrict__ batch,
                                                   uint32* __restrict__ hout,
                                                   float* __restrict__ pooled, int n) {
    __shared__ float red[8][64];
    __shared__ int sg[8];
    int tid = threadIdx.x;
    int wave = tid >> 6;
    int lane = tid & 63;
    int half = lane >> 5;
    int hl = lane & 31;
    int slot = wave * 2 + half;
    int node = blockIdx.x * 8 + slot;
    bool active = node < n;
    float o0 = 0.f, o1 = 0.f;
    if (active) {
        int r0 = rowptr[node];
        int r1 = rowptr[node + 1];
        uint32 sv = h[(size_t)node * 32 + hl];
        float acc0 = bf16lo(sv);
        float acc1 = bf16hi(sv);
        int m = r1 - 1;
        for (int e = r0; e < r1; e += 4) {
            int e1 = min(e + 1, m);
            int e2 = min(e + 2, m);
            int e3 = min(e + 3, m);
            int s0 = csrs[e];
            int s1 = csrs[e1];
            int s2 = csrs[e2];
            int s3 = csrs[e3];
            uint32 g0 = h[(size_t)s0 * 32 + hl];
            uint32 g1 = h[(size_t)s1 * 32 + hl];
            uint32 g2 = h[(size_t)s2 * 32 + hl];
            uint32 g3 = h[(size_t)s3 * 32 + hl];
            if (e + 1 > m) g1 = 0u;
            if (e + 2 > m) g2 = 0u;
            if (e + 3 > m) g3 = 0u;
            acc0 += (bf16lo(g0) + bf16lo(g1)) + (bf16lo(g2) + bf16lo(g3));
            acc1 += (bf16hi(g0) + bf16hi(g1)) + (bf16hi(g2) + bf16hi(g3));
        }
        float dd = dinv[node];
        o0 = acc0 * dd + b[2 * hl + 0];
        o1 = acc1 * dd + b[2 * hl + 1];
        o0 = o0 > 0.f ? o0 : 0.f;
        o1 = o1 > 0.f ? o1 : 0.f;
        if (!DOPOOL) hout[(size_t)node * 32 + hl] = packbf16(o0, o1);
    }
    if (DOPOOL) {
        red[slot][2 * hl + 0] = active ? o0 : 0.f;
        red[slot][2 * hl + 1] = active ? o1 : 0.f;
        if (hl == 0) sg[slot] = active ? batch[node] : -1;
        __syncthreads();
        if (wave == 0) {
            float s = red[0][lane];
            int gcur = sg[0];
            for (int w = 1; w < 8; ++w) {
                int gw = sg[w];
                if (gw < 0) break;
                if (gw == gcur) {
                    s += red[w][lane];
                } else {
                    if (gcur >= 0) atomicAdd(&pooled[gcur * H + lane], s);
                    s = red[w][lane];
                    gcur = gw;
                }
            }
            if (gcur >= 0) atomicAdd(&pooled[gcur * H + lane], s);
        }
    }
}

// ---------------- final linear ----------------
__global__ void k_final(const float* __restrict__ pooled, const float* __restrict__ gf,
                        const float* __restrict__ Wlin, const float* __restrict__ blin,
                        float* __restrict__ out) {
    int t = threadIdx.x;
    if (t >= G * OUT) return;
    int g = t >> 1, o = t & 1;
    float acc = blin[o];
#pragma unroll
    for (int j = 0; j < 64; ++j) acc += pooled[g * H + j] * Wlin[j * OUT + o];
    acc += gf[g] * Wlin[64 * OUT + o];
    out[g * OUT + o] = acc;
}

extern "C" void kernel_launch(void* const* d_in, const int* in_sizes, int n_in,
                              void* d_out, int out_size, void* d_ws, size_t ws_size,
                              hipStream_t stream) {
    const float* x          = (const float*)d_in[0];
    const int*   edge_index = (const int*)d_in[1];
    const int*   batch      = (const int*)d_in[2];
    const float* gf         = (const float*)d_in[3];
    const float* W1         = (const float*)d_in[4];
    const float* b1         = (const float*)d_in[5];
    const float* W2         = (const float*)d_in[6];
    const float* b2         = (const float*)d_in[7];
    const float* Wlin       = (const float*)d_in[8];
    const float* blin       = (const float*)d_in[9];
    float* out = (float*)d_out;

    const int N = in_sizes[0] / H;
    const int E = in_sizes[1] / 2;
    const int* src = edge_index;
    const int* dst = edge_index + E;

    // workspace layout
    float* ws = (float*)d_ws;
    float* dinv   = ws;                         // N
    uint32* bufA  = (uint32*)(dinv + N);        // N*32 uints (bf16 packed)
    uint32* bufB  = bufA + (size_t)N * 32;      // N*32 uints
    float* pooled = (float*)(bufB + (size_t)N * 32);  // G*H
    int*   counts = (int*)(pooled + G * H);     // N
    int*   rowptr = counts + N;                 // N+1
    int*   cursor = rowptr + (N + 1);           // N
    int*   blocksums = cursor + N;              // 256
    size_t off = (size_t)(blocksums + 256 - (int*)d_ws);
    off = (off + 3) & ~(size_t)3;               // 16B align for uint4 loads
    uint32* Wb   = (uint32*)d_ws + off;         // 2 * 2048 uints (B-frags for W1,W2)
    int*   csrs  = (int*)(Wb + 2 * 2048);       // E ints

    const int T = 256;
    const int NB = (N + TILE - 1) / TILE;       // <=256 required
    const int PSIZE = (N + 7) / 8;              // nodes per XCD partition
    const int MP = 64;                          // blocks per partition

    // CSR build (also produces dinv from in-degree+1)
    k_zero_int<<<(N + T - 1) / T, T, 0, stream>>>(counts, N);
    k_hist_part<<<8 * MP, T, 0, stream>>>(dst, counts, E, PSIZE);
    k_scan1<<<NB, TILE, 0, stream>>>(counts, rowptr, blocksums, N);
    k_scan2<<<1, 256, 0, stream>>>(blocksums, NB);
    k_scan3<<<NB, TILE, 0, stream>>>(counts, rowptr, cursor, dinv, blocksums, N, E);
    k_fill_part<<<8 * MP, T, 0, stream>>>(src, dst, cursor, csrs, E, PSIZE);

    // weight packing + pooled zero
    k_prepW<<<1, 64, 0, stream>>>(W1, Wb);
    k_prepW<<<1, 64, 0, stream>>>(W2, Wb + 2048);
    k_zero<<<(G * H + T - 1) / T, T, 0, stream>>>(pooled, G * H);

    const int NBG = (N + 127) / 128;

    // layer 1
    k_gemm_mfma<0><<<NBG, T, 0, stream>>>(x, Wb, dinv, bufA, N);
    k_aggregate<0><<<(N + 7) / 8, T, 0, stream>>>(bufA, csrs, rowptr, dinv, b1, batch,
                                                  bufB, pooled, N);

    // layer 2 + fused pool
    k_gemm_mfma<1><<<NBG, T, 0, stream>>>(bufB, Wb + 2048, dinv, bufA, N);
    k_aggregate<1><<<(N + 7) / 8, T, 0, stream>>>(bufA, csrs, rowptr, dinv, b2, batch,
                                                  nullptr, pooled, N);

    // head
    k_final<<<1, 128, 0, stream>>>(pooled, gf, Wlin, blin, out);
}

// Round 10
// 211.726 us; speedup vs baseline: 1.6386x; 1.0137x over previous
//
#include <hip/hip_runtime.h>

#define H 64
#define G 64
#define OUT 2
#define TILE 1024

typedef unsigned int uint32;
using short8 = __attribute__((ext_vector_type(8))) short;
using f32x4  = __attribute__((ext_vector_type(4))) float;

union ABFrag { uint32 u[4]; uint4 q; short8 v; };

__device__ inline float bf16lo(uint32 u) { return __uint_as_float(u << 16); }
__device__ inline float bf16hi(uint32 u) { return __uint_as_float(u & 0xffff0000u); }
__device__ inline uint32 packbf16(float a, float b) {
    uint32 ua = __float_as_uint(a);
    uint32 ub = __float_as_uint(b);
    ua = (ua + 0x7fffu + ((ua >> 16) & 1u)) >> 16;                 // RNE
    ub = (ub + 0x7fffu + ((ub >> 16) & 1u)) & 0xffff0000u;         // RNE
    return ua | ub;
}

// ---------------- zero ----------------
__global__ void k_zero_int(int* p, int n) {
    int i = blockIdx.x * blockDim.x + threadIdx.x;
    if (i < n) p[i] = 0;
}

__global__ void k_zero(float* p, int n) {
    int i = blockIdx.x * blockDim.x + threadIdx.x;
    if (i < n) p[i] = 0.0f;
}

// ---------------- XCD-partitioned in-degree histogram ----------------
// Streaming edge reads are NON-TEMPORAL so they don't evict the dirty
// counts lines from this XCD's L2 (write-combining stays intact).
__global__ __launch_bounds__(256) void k_hist_part(const int* __restrict__ dst,
                                                   int* __restrict__ counts,
                                                   int e, int psize) {
    int part = blockIdx.x & 7;
    int blk  = blockIdx.x >> 3;
    int nblk = gridDim.x >> 3;
    int lo = part * psize, hi = lo + psize;
    int stride = nblk * 256;
    for (int i = blk * 256 + threadIdx.x; i < e; i += stride) {
        int d = __builtin_nontemporal_load(&dst[i]);
        if (d >= lo && d < hi) atomicAdd(&counts[d], 1);
    }
}

// ---------------- 3-phase device-wide exclusive scan ----------------
__global__ __launch_bounds__(TILE) void k_scan1(const int* __restrict__ counts,
                                                int* __restrict__ rowptr,
                                                int* __restrict__ blocksums, int n) {
    __shared__ int sm[TILE];
    int t = threadIdx.x;
    int i = blockIdx.x * TILE + t;
    int v = (i < n) ? counts[i] : 0;
    sm[t] = v;
    __syncthreads();
    for (int off = 1; off < TILE; off <<= 1) {
        int u = (t >= off) ? sm[t - off] : 0;
        __syncthreads();
        sm[t] += u;
        __syncthreads();
    }
    if (i < n) rowptr[i] = sm[t] - v;  // exclusive
    if (t == TILE - 1) blocksums[blockIdx.x] = sm[t];
}

__global__ __launch_bounds__(256) void k_scan2(int* __restrict__ blocksums, int nb) {
    __shared__ int sm[256];
    int t = threadIdx.x;
    int v = (t < nb) ? blocksums[t] : 0;
    sm[t] = v;
    __syncthreads();
    for (int off = 1; off < 256; off <<= 1) {
        int u = (t >= off) ? sm[t - off] : 0;
        __syncthreads();
        sm[t] += u;
        __syncthreads();
    }
    if (t < nb) blocksums[t] = sm[t] - v;
}

__global__ __launch_bounds__(TILE) void k_scan3(const int* __restrict__ counts,
                                                int* __restrict__ rowptr,
                                                int* __restrict__ cursor,
                                                float* __restrict__ dinv,
                                                const int* __restrict__ blocksums,
                                                int n, int e_total) {
    int i = blockIdx.x * TILE + threadIdx.x;
    if (i < n) {
        int r = rowptr[i] + blocksums[blockIdx.x];
        rowptr[i] = r;
        cursor[i] = r;
        dinv[i] = rsqrtf((float)counts[i] + 1.0f);
    }
    if (i == 0) rowptr[n] = e_total;
}

// ---------------- XCD-partitioned CSR fill (non-temporal edge streaming) ----------------
__global__ __launch_bounds__(256) void k_fill_part(const int* __restrict__ src,
                                                   const int* __restrict__ dst,
                                                   int* __restrict__ cursor,
                                                   int* __restrict__ csrs,
                                                   int e, int psize) {
    int part = blockIdx.x & 7;
    int blk  = blockIdx.x >> 3;
    int nblk = gridDim.x >> 3;
    int lo = part * psize, hi = lo + psize;
    int stride = nblk * 256;
    for (int i = blk * 256 + threadIdx.x; i < e; i += stride) {
        int d = __builtin_nontemporal_load(&dst[i]);
        if (d >= lo && d < hi) {
            int s = __builtin_nontemporal_load(&src[i]);
            int pos = atomicAdd(&cursor[d], 1);
            csrs[pos] = s;
        }
    }
}

// ---------------- pack W into MFMA B-fragment layout (bf16) ----------------
__global__ void k_prepW(const float* __restrict__ W, uint32* __restrict__ Wb) {
    int lane = threadIdx.x;  // 64 threads
    for (int ct = 0; ct < 4; ++ct)
        for (int ks = 0; ks < 2; ++ks) {
            int col = ct * 16 + (lane & 15);
            int k0 = ks * 32 + (lane >> 4) * 8;
            int slot = ct * 2 + ks;
            for (int r = 0; r < 4; ++r) {
                float a = W[(k0 + 2 * r) * 64 + col];
                float b = W[(k0 + 2 * r + 1) * 64 + col];
                Wb[(slot * 64 + lane) * 4 + r] = packbf16(a, b);
            }
        }
}

// ---------------- MFMA GEMM: Y(bf16,[n,64]) = (X[n,64] @ W) * dinv[row] ----------------
template <int BFIN>
__global__ __launch_bounds__(256) void k_gemm_mfma(const void* __restrict__ Xv,
                                                   const uint32* __restrict__ Wb,
                                                   const float* __restrict__ dinv,
                                                   uint32* __restrict__ Y, int n) {
    int lane = threadIdx.x & 63;
    int wave = threadIdx.x >> 6;
    int l15 = lane & 15;
    int grp = lane >> 4;  // 0..3
    ABFrag bf[4][2];
    const uint4* Wb4 = (const uint4*)Wb;
#pragma unroll
    for (int ct = 0; ct < 4; ++ct)
#pragma unroll
        for (int ks = 0; ks < 2; ++ks)
            bf[ct][ks].q = Wb4[(ct * 2 + ks) * 64 + lane];

    int rbase0 = blockIdx.x * 128 + wave * 32;
    f32x4 acc[2][4] = {};
#pragma unroll
    for (int sub = 0; sub < 2; ++sub) {
        int row = min(rbase0 + sub * 16 + l15, n - 1);
        ABFrag a[2];
        if (BFIN) {
            const uint4* X4 = (const uint4*)Xv;
#pragma unroll
            for (int ks = 0; ks < 2; ++ks)
                a[ks].q = X4[(size_t)row * 8 + ks * 4 + grp];
        } else {
            const float4* X4 = (const float4*)Xv;
#pragma unroll
            for (int ks = 0; ks < 2; ++ks) {
                float4 f0 = X4[(size_t)row * 16 + ks * 8 + grp * 2];
                float4 f1 = X4[(size_t)row * 16 + ks * 8 + grp * 2 + 1];
                a[ks].u[0] = packbf16(f0.x, f0.y);
                a[ks].u[1] = packbf16(f0.z, f0.w);
                a[ks].u[2] = packbf16(f1.x, f1.y);
                a[ks].u[3] = packbf16(f1.z, f1.w);
            }
        }
#pragma unroll
        for (int ct = 0; ct < 4; ++ct) {
            acc[sub][ct] = __builtin_amdgcn_mfma_f32_16x16x32_bf16(a[0].v, bf[ct][0].v,
                                                                   acc[sub][ct], 0, 0, 0);
            acc[sub][ct] = __builtin_amdgcn_mfma_f32_16x16x32_bf16(a[1].v, bf[ct][1].v,
                                                                   acc[sub][ct], 0, 0, 0);
        }
    }
#pragma unroll
    for (int sub = 0; sub < 2; ++sub) {
        int rb = rbase0 + sub * 16;
#pragma unroll
        for (int r = 0; r < 4; ++r) {
            int row = rb + grp * 4 + r;
            float dd = dinv[min(row, n - 1)];
#pragma unroll
            for (int ct = 0; ct < 4; ++ct) {
                float v = acc[sub][ct][r] * dd;
                float w = __shfl_xor(v, 1);
                if (!(lane & 1) && row < n)
                    Y[(size_t)row * 32 + ct * 8 + (l15 >> 1)] = packbf16(v, w);
            }
        }
    }
}

// ---------------- fused aggregate: out = relu(dinv_d*(hs_d + sum hs_src) + b) ----------------
template <int DOPOOL>
__global__ __launch_bounds__(256) void k_aggregate(const uint32* __restrict__ h,
                                                   const int* __restrict__ csrs,
                                                   const int* __restrict__ rowptr,
                                                   const float* __restrict__ dinv,
                                                   const float* __restrict__ b,
                                                   const int* __restrict__ batch,
                                                   uint32* __restrict__ hout,
                                                   float* __restrict__ pooled, int n) {
    __shared__ float red[8][64];
    __shared__ int sg[8];
    int tid = threadIdx.x;
    int wave = tid >> 6;
    int lane = tid & 63;
    int half = lane >> 5;
    int hl = lane & 31;
    int slot = wave * 2 + half;
    int node = blockIdx.x * 8 + slot;
    bool active = node < n;
    float o0 = 0.f, o1 = 0.f;
    if (active) {
        int r0 = rowptr[node];
        int r1 = rowptr[node + 1];
        uint32 sv = h[(size_t)node * 32 + hl];
        float acc0 = bf16lo(sv);
        float acc1 = bf16hi(sv);
        int m = r1 - 1;
        for (int e = r0; e < r1; e += 4) {
            int e1 = min(e + 1, m);
            int e2 = min(e + 2, m);
            int e3 = min(e + 3, m);
            int s0 = csrs[e];
            int s1 = csrs[e1];
            int s2 = csrs[e2];
            int s3 = csrs[e3];
            uint32 g0 = h[(size_t)s0 * 32 + hl];
            uint32 g1 = h[(size_t)s1 * 32 + hl];
            uint32 g2 = h[(size_t)s2 * 32 + hl];
            uint32 g3 = h[(size_t)s3 * 32 + hl];
            if (e + 1 > m) g1 = 0u;
            if (e + 2 > m) g2 = 0u;
            if (e + 3 > m) g3 = 0u;
            acc0 += (bf16lo(g0) + bf16lo(g1)) + (bf16lo(g2) + bf16lo(g3));
            acc1 += (bf16hi(g0) + bf16hi(g1)) + (bf16hi(g2) + bf16hi(g3));
        }
        float dd = dinv[node];
        o0 = acc0 * dd + b[2 * hl + 0];
        o1 = acc1 * dd + b[2 * hl + 1];
        o0 = o0 > 0.f ? o0 : 0.f;
        o1 = o1 > 0.f ? o1 : 0.f;
        if (!DOPOOL) hout[(size_t)node * 32 + hl] = packbf16(o0, o1);
    }
    if (DOPOOL) {
        red[slot][2 * hl + 0] = active ? o0 : 0.f;
        red[slot][2 * hl + 1] = active ? o1 : 0.f;
        if (hl == 0) sg[slot] = active ? batch[node] : -1;
        __syncthreads();
        if (wave == 0) {
            float s = red[0][lane];
            int gcur = sg[0];
            for (int w = 1; w < 8; ++w) {
                int gw = sg[w];
                if (gw < 0) break;
                if (gw == gcur) {
                    s += red[w][lane];
                } else {
                    if (gcur >= 0) atomicAdd(&pooled[gcur * H + lane], s);
                    s = red[w][lane];
                    gcur = gw;
                }
            }
            if (gcur >= 0) atomicAdd(&pooled[gcur * H + lane], s);
        }
    }
}

// ---------------- final linear ----------------
__global__ void k_final(const float* __restrict__ pooled, const float* __restrict__ gf,
                        const float* __restrict__ Wlin, const float* __restrict__ blin,
                        float* __restrict__ out) {
    int t = threadIdx.x;
    if (t >= G * OUT) return;
    int g = t >> 1, o = t & 1;
    float acc = blin[o];
#pragma unroll
    for (int j = 0; j < 64; ++j) acc += pooled[g * H + j] * Wlin[j * OUT + o];
    acc += gf[g] * Wlin[64 * OUT + o];
    out[g * OUT + o] = acc;
}

extern "C" void kernel_launch(void* const* d_in, const int* in_sizes, int n_in,
                              void* d_out, int out_size, void* d_ws, size_t ws_size,
                              hipStream_t stream) {
    const float* x          = (const float*)d_in[0];
    const int*   edge_index = (const int*)d_in[1];
    const int*   batch      = (const int*)d_in[2];
    const float* gf         = (const float*)d_in[3];
    const float* W1         = (const float*)d_in[4];
    const float* b1         = (const float*)d_in[5];
    const float* W2         = (const float*)d_in[6];
    const float* b2         = (const float*)d_in[7];
    const float* Wlin       = (const float*)d_in[8];
    const float* blin       = (const float*)d_in[9];
    float* out = (float*)d_out;

    const int N = in_sizes[0] / H;
    const int E = in_sizes[1] / 2;
    const int* src = edge_index;
    const int* dst = edge_index + E;

    // workspace layout
    float* ws = (float*)d_ws;
    float* dinv   = ws;                         // N
    uint32* bufA  = (uint32*)(dinv + N);        // N*32 uints (bf16 packed)
    uint32* bufB  = bufA + (size_t)N * 32;      // N*32 uints
    float* pooled = (float*)(bufB + (size_t)N * 32);  // G*H
    int*   counts = (int*)(pooled + G * H);     // N
    int*   rowptr = counts + N;                 // N+1
    int*   cursor = rowptr + (N + 1);           // N
    int*   blocksums = cursor + N;              // 256
    size_t off = (size_t)(blocksums + 256 - (int*)d_ws);
    off = (off + 3) & ~(size_t)3;               // 16B align for uint4 loads
    uint32* Wb   = (uint32*)d_ws + off;         // 2 * 2048 uints (B-frags for W1,W2)
    int*   csrs  = (int*)(Wb + 2 * 2048);       // E ints

    const int T = 256;
    const int NB = (N + TILE - 1) / TILE;       // <=256 required
    const int PSIZE = (N + 7) / 8;              // nodes per XCD partition
    const int MP = 128;                         // blocks per partition

    // CSR build (also produces dinv from in-degree+1)
    k_zero_int<<<(N + T - 1) / T, T, 0, stream>>>(counts, N);
    k_hist_part<<<8 * MP, T, 0, stream>>>(dst, counts, E, PSIZE);
    k_scan1<<<NB, TILE, 0, stream>>>(counts, rowptr, blocksums, N);
    k_scan2<<<1, 256, 0, stream>>>(blocksums, NB);
    k_scan3<<<NB, TILE, 0, stream>>>(counts, rowptr, cursor, dinv, blocksums, N, E);
    k_fill_part<<<8 * MP, T, 0, stream>>>(src, dst, cursor, csrs, E, PSIZE);

    // weight packing + pooled zero
    k_prepW<<<1, 64, 0, stream>>>(W1, Wb);
    k_prepW<<<1, 64, 0, stream>>>(W2, Wb + 2048);
    k_zero<<<(G * H + T - 1) / T, T, 0, stream>>>(pooled, G * H);

    const int NBG = (N + 127) / 128;

    // layer 1
    k_gemm_mfma<0><<<NBG, T, 0, stream>>>(x, Wb, dinv, bufA, N);
    k_aggregate<0><<<(N + 7) / 8, T, 0, stream>>>(bufA, csrs, rowptr, dinv, b1, batch,
                                                  bufB, pooled, N);

    // layer 2 + fused pool
    k_gemm_mfma<1><<<NBG, T, 0, stream>>>(bufB, Wb + 2048, dinv, bufA, N);
    k_aggregate<1><<<(N + 7) / 8, T, 0, stream>>>(bufA, csrs, rowptr, dinv, b2, batch,
                                                  nullptr, pooled, N);

    // head
    k_final<<<1, 128, 0, stream>>>(pooled, gf, Wlin, blin, out);
}

// Round 11
// 179.746 us; speedup vs baseline: 1.9301x; 1.1779x over previous
//
#include <hip/hip_runtime.h>

#define H 64
#define G 64
#define OUT 2
#define MAXBUK 128
#define BSHIFT 10
#define CAP 12288

typedef unsigned int uint32;
using short8 = __attribute__((ext_vector_type(8))) short;
using f32x4  = __attribute__((ext_vector_type(4))) float;

union ABFrag { uint32 u[4]; uint4 q; short8 v; };

__device__ inline float bf16lo(uint32 u) { return __uint_as_float(u << 16); }
__device__ inline float bf16hi(uint32 u) { return __uint_as_float(u & 0xffff0000u); }
__device__ inline uint32 packbf16(float a, float b) {
    uint32 ua = __float_as_uint(a);
    uint32 ub = __float_as_uint(b);
    ua = (ua + 0x7fffu + ((ua >> 16) & 1u)) >> 16;                 // RNE
    ub = (ub + 0x7fffu + ((ub >> 16) & 1u)) & 0xffff0000u;         // RNE
    return ua | ub;
}

// ---------------- zero ----------------
__global__ void k_zero_int(int* p, int n) {
    int i = blockIdx.x * blockDim.x + threadIdx.x;
    if (i < n) p[i] = 0;
}

__global__ void k_zero(float* p, int n) {
    int i = blockIdx.x * blockDim.x + threadIdx.x;
    if (i < n) p[i] = 0.0f;
}

// ---------------- bucket histogram (LDS-private, tiny merge) ----------------
__global__ __launch_bounds__(256) void k_bhist(const int* __restrict__ dst,
                                               int* __restrict__ bcnt, int e, int nbuk) {
    __shared__ int h[MAXBUK];
    for (int i = threadIdx.x; i < MAXBUK; i += 256) h[i] = 0;
    __syncthreads();
    int stride = gridDim.x * 256;
    for (int i = blockIdx.x * 256 + threadIdx.x; i < e; i += stride)
        atomicAdd(&h[__builtin_nontemporal_load(&dst[i]) >> BSHIFT], 1);
    __syncthreads();
    for (int i = threadIdx.x; i < nbuk; i += 256)
        if (h[i]) atomicAdd(&bcnt[i], h[i]);
}

// ---------------- scan bucket totals (98 values; serial is fine) ----------------
__global__ void k_bscan(const int* __restrict__ bcnt, int* __restrict__ bbase,
                        int* __restrict__ bcur, int nbuk) {
    if (threadIdx.x == 0) {
        int run = 0;
        for (int i = 0; i < nbuk; ++i) {
            bbase[i] = run; bcur[i] = run; run += bcnt[i];
        }
        bbase[nbuk] = run;
    }
}

// ---------------- bucket scatter: (src,dst) -> inter, contiguous runs ----------------
__global__ __launch_bounds__(256) void k_bscatter(const int* __restrict__ src,
                                                  const int* __restrict__ dst,
                                                  int* __restrict__ bcur,
                                                  int2* __restrict__ inter, int e) {
    __shared__ int cnt[MAXBUK];
    __shared__ int run[MAXBUK];
    int per = (e + gridDim.x - 1) / gridDim.x;
    int lo = blockIdx.x * per, hi = min(lo + per, e);
    for (int i = threadIdx.x; i < MAXBUK; i += 256) cnt[i] = 0;
    __syncthreads();
    for (int i = lo + threadIdx.x; i < hi; i += 256)
        atomicAdd(&cnt[dst[i] >> BSHIFT], 1);
    __syncthreads();
    if (threadIdx.x < MAXBUK) {
        int c = cnt[threadIdx.x];
        run[threadIdx.x] = c ? atomicAdd(&bcur[threadIdx.x], c) : 0;
        cnt[threadIdx.x] = 0;
    }
    __syncthreads();
    for (int i = lo + threadIdx.x; i < hi; i += 256) {
        int d = dst[i];
        int s = src[i];
        int b = d >> BSHIFT;
        int pos = run[b] + atomicAdd(&cnt[b], 1);
        inter[pos] = make_int2(s, d);
    }
}

// ---------------- per-bucket CSR build: rowptr + dinv + staged coalesced csr ----------------
__global__ __launch_bounds__(256) void k_build(const int2* __restrict__ inter,
                                               const int* __restrict__ bbase,
                                               int* __restrict__ rowptr,
                                               float* __restrict__ dinv,
                                               int* __restrict__ csr,
                                               int n, int nbuk) {
    __shared__ int cnt[1024];
    __shared__ int scn[1024];
    __shared__ int part[256];
    __shared__ int stage[CAP];
    int b = blockIdx.x;
    int t = threadIdx.x;
    int nlo = b << BSHIFT;
    int nhi = min(nlo + 1024, n);
    int nn = nhi - nlo;
    int e0 = bbase[b], e1 = bbase[b + 1];
    int ne = e1 - e0;
    for (int i = t; i < nn; i += 256) cnt[i] = 0;
    __syncthreads();
    for (int i = t; i < ne; i += 256)
        atomicAdd(&cnt[inter[e0 + i].y - nlo], 1);
    __syncthreads();
    // exclusive scan over nn (<=1024): 4 per thread + Hillis-Steele on partials
    int base4 = 4 * t;
    int sum = 0;
    for (int j = 0; j < 4; ++j) {
        int idx = base4 + j;
        int v = (idx < nn) ? cnt[idx] : 0;
        if (idx < nn) scn[idx] = sum;
        sum += v;
    }
    part[t] = sum;
    __syncthreads();
    for (int off = 1; off < 256; off <<= 1) {
        int v = (t >= off) ? part[t - off] : 0;
        __syncthreads();
        part[t] += v;
        __syncthreads();
    }
    int pbase = (t == 0) ? 0 : part[t - 1];
    for (int j = 0; j < 4; ++j) {
        int idx = base4 + j;
        if (idx < nn) scn[idx] += pbase;
    }
    __syncthreads();
    // rowptr + dinv (coalesced)
    for (int i = t; i < nn; i += 256) {
        rowptr[nlo + i] = e0 + scn[i];
        dinv[nlo + i] = rsqrtf((float)cnt[i] + 1.0f);
    }
    if (b == 0 && t == 0) rowptr[n] = bbase[nbuk];
    // reuse cnt as cursor
    for (int i = t; i < nn; i += 256) cnt[i] = 0;
    __syncthreads();
    // scatter into LDS stage (rare overflow -> direct global)
    for (int i = t; i < ne; i += 256) {
        int2 p = inter[e0 + i];
        int ln = p.y - nlo;
        int pos = scn[ln] + atomicAdd(&cnt[ln], 1);
        if (pos < CAP) stage[pos] = p.x;
        else csr[e0 + pos] = p.x;
    }
    __syncthreads();
    int m = min(ne, CAP);
    for (int i = t; i < m; i += 256) csr[e0 + i] = stage[i];  // coalesced
}

// ---------------- pack W into MFMA B-fragment layout (bf16) ----------------
__global__ void k_prepW(const float* __restrict__ W, uint32* __restrict__ Wb) {
    int lane = threadIdx.x;  // 64 threads
    for (int ct = 0; ct < 4; ++ct)
        for (int ks = 0; ks < 2; ++ks) {
            int col = ct * 16 + (lane & 15);
            int k0 = ks * 32 + (lane >> 4) * 8;
            int slot = ct * 2 + ks;
            for (int r = 0; r < 4; ++r) {
                float a = W[(k0 + 2 * r) * 64 + col];
                float b = W[(k0 + 2 * r + 1) * 64 + col];
                Wb[(slot * 64 + lane) * 4 + r] = packbf16(a, b);
            }
        }
}

// ---------------- MFMA GEMM: Y(bf16,[n,64]) = (X[n,64] @ W) * dinv[row] ----------------
template <int BFIN>
__global__ __launch_bounds__(256) void k_gemm_mfma(const void* __restrict__ Xv,
                                                   const uint32* __restrict__ Wb,
                                                   const float* __restrict__ dinv,
                                                   uint32* __restrict__ Y, int n) {
    int lane = threadIdx.x & 63;
    int wave = threadIdx.x >> 6;
    int l15 = lane & 15;
    int grp = lane >> 4;  // 0..3
    ABFrag bf[4][2];
    const uint4* Wb4 = (const uint4*)Wb;
#pragma unroll
    for (int ct = 0; ct < 4; ++ct)
#pragma unroll
        for (int ks = 0; ks < 2; ++ks)
            bf[ct][ks].q = Wb4[(ct * 2 + ks) * 64 + lane];

    int rbase0 = blockIdx.x * 128 + wave * 32;
    f32x4 acc[2][4] = {};
#pragma unroll
    for (int sub = 0; sub < 2; ++sub) {
        int row = min(rbase0 + sub * 16 + l15, n - 1);
        ABFrag a[2];
        if (BFIN) {
            const uint4* X4 = (const uint4*)Xv;
#pragma unroll
            for (int ks = 0; ks < 2; ++ks)
                a[ks].q = X4[(size_t)row * 8 + ks * 4 + grp];
        } else {
            const float4* X4 = (const float4*)Xv;
#pragma unroll
            for (int ks = 0; ks < 2; ++ks) {
                float4 f0 = X4[(size_t)row * 16 + ks * 8 + grp * 2];
                float4 f1 = X4[(size_t)row * 16 + ks * 8 + grp * 2 + 1];
                a[ks].u[0] = packbf16(f0.x, f0.y);
                a[ks].u[1] = packbf16(f0.z, f0.w);
                a[ks].u[2] = packbf16(f1.x, f1.y);
                a[ks].u[3] = packbf16(f1.z, f1.w);
            }
        }
#pragma unroll
        for (int ct = 0; ct < 4; ++ct) {
            acc[sub][ct] = __builtin_amdgcn_mfma_f32_16x16x32_bf16(a[0].v, bf[ct][0].v,
                                                                   acc[sub][ct], 0, 0, 0);
            acc[sub][ct] = __builtin_amdgcn_mfma_f32_16x16x32_bf16(a[1].v, bf[ct][1].v,
                                                                   acc[sub][ct], 0, 0, 0);
        }
    }
#pragma unroll
    for (int sub = 0; sub < 2; ++sub) {
        int rb = rbase0 + sub * 16;
#pragma unroll
        for (int r = 0; r < 4; ++r) {
            int row = rb + grp * 4 + r;
            float dd = dinv[min(row, n - 1)];
#pragma unroll
            for (int ct = 0; ct < 4; ++ct) {
                float v = acc[sub][ct][r] * dd;
                float w = __shfl_xor(v, 1);
                if (!(lane & 1) && row < n)
                    Y[(size_t)row * 32 + ct * 8 + (l15 >> 1)] = packbf16(v, w);
            }
        }
    }
}

// ---------------- fused aggregate: out = relu(dinv_d*(hs_d + sum hs_src) + b) ----------------
template <int DOPOOL>
__global__ __launch_bounds__(256) void k_aggregate(const uint32* __restrict__ h,
                                                   const int* __restrict__ csrs,
                                                   const int* __restrict__ rowptr,
                                                   const float* __restrict__ dinv,
                                                   const float* __restrict__ b,
                                                   const int* __restrict__ batch,
                                                   uint32* __restrict__ hout,
                                                   float* __restrict__ pooled, int n) {
    __shared__ float red[8][64];
    __shared__ int sg[8];
    int tid = threadIdx.x;
    int wave = tid >> 6;
    int lane = tid & 63;
    int half = lane >> 5;
    int hl = lane & 31;
    int slot = wave * 2 + half;
    int node = blockIdx.x * 8 + slot;
    bool active = node < n;
    float o0 = 0.f, o1 = 0.f;
    if (active) {
        int r0 = rowptr[node];
        int r1 = rowptr[node + 1];
        uint32 sv = h[(size_t)node * 32 + hl];
        float acc0 = bf16lo(sv);
        float acc1 = bf16hi(sv);
        int m = r1 - 1;
        for (int e = r0; e < r1; e += 4) {
            int e1 = min(e + 1, m);
            int e2 = min(e + 2, m);
            int e3 = min(e + 3, m);
            int s0 = csrs[e];
            int s1 = csrs[e1];
            int s2 = csrs[e2];
            int s3 = csrs[e3];
            uint32 g0 = h[(size_t)s0 * 32 + hl];
            uint32 g1 = h[(size_t)s1 * 32 + hl];
            uint32 g2 = h[(size_t)s2 * 32 + hl];
            uint32 g3 = h[(size_t)s3 * 32 + hl];
            if (e + 1 > m) g1 = 0u;
            if (e + 2 > m) g2 = 0u;
            if (e + 3 > m) g3 = 0u;
            acc0 += (bf16lo(g0) + bf16lo(g1)) + (bf16lo(g2) + bf16lo(g3));
            acc1 += (bf16hi(g0) + bf16hi(g1)) + (bf16hi(g2) + bf16hi(g3));
        }
        float dd = dinv[node];
        o0 = acc0 * dd + b[2 * hl + 0];
        o1 = acc1 * dd + b[2 * hl + 1];
        o0 = o0 > 0.f ? o0 : 0.f;
        o1 = o1 > 0.f ? o1 : 0.f;
        if (!DOPOOL) hout[(size_t)node * 32 + hl] = packbf16(o0, o1);
    }
    if (DOPOOL) {
        red[slot][2 * hl + 0] = active ? o0 : 0.f;
        red[slot][2 * hl + 1] = active ? o1 : 0.f;
        if (hl == 0) sg[slot] = active ? batch[node] : -1;
        __syncthreads();
        if (wave == 0) {
            float s = red[0][lane];
            int gcur = sg[0];
            for (int w = 1; w < 8; ++w) {
                int gw = sg[w];
                if (gw < 0) break;
                if (gw == gcur) {
                    s += red[w][lane];
                } else {
                    if (gcur >= 0) atomicAdd(&pooled[gcur * H + lane], s);
                    s = red[w][lane];
                    gcur = gw;
                }
            }
            if (gcur >= 0) atomicAdd(&pooled[gcur * H + lane], s);
        }
    }
}

// ---------------- final linear ----------------
__global__ void k_final(const float* __restrict__ pooled, const float* __restrict__ gf,
                        const float* __restrict__ Wlin, const float* __restrict__ blin,
                        float* __restrict__ out) {
    int t = threadIdx.x;
    if (t >= G * OUT) return;
    int g = t >> 1, o = t & 1;
    float acc = blin[o];
#pragma unroll
    for (int j = 0; j < 64; ++j) acc += pooled[g * H + j] * Wlin[j * OUT + o];
    acc += gf[g] * Wlin[64 * OUT + o];
    out[g * OUT + o] = acc;
}

extern "C" void kernel_launch(void* const* d_in, const int* in_sizes, int n_in,
                              void* d_out, int out_size, void* d_ws, size_t ws_size,
                              hipStream_t stream) {
    const float* x          = (const float*)d_in[0];
    const int*   edge_index = (const int*)d_in[1];
    const int*   batch      = (const int*)d_in[2];
    const float* gf         = (const float*)d_in[3];
    const float* W1         = (const float*)d_in[4];
    const float* b1         = (const float*)d_in[5];
    const float* W2         = (const float*)d_in[6];
    const float* b2         = (const float*)d_in[7];
    const float* Wlin       = (const float*)d_in[8];
    const float* blin       = (const float*)d_in[9];
    float* out = (float*)d_out;

    const int N = in_sizes[0] / H;
    const int E = in_sizes[1] / 2;
    const int* src = edge_index;
    const int* dst = edge_index + E;
    const int NBUK = (N + (1 << BSHIFT) - 1) >> BSHIFT;  // 98 for N=100k (<=MAXBUK)

    // workspace layout
    float* ws = (float*)d_ws;
    float* dinv   = ws;                         // N
    uint32* bufA  = (uint32*)(dinv + N);        // N*32 uints (bf16 packed)
    uint32* bufB  = bufA + (size_t)N * 32;      // N*32 uints
    float* pooled = (float*)(bufB + (size_t)N * 32);  // G*H
    int*   rowptr = (int*)(pooled + G * H);     // N+1
    int*   bcnt   = rowptr + (N + 1);           // MAXBUK
    int*   bbase  = bcnt + MAXBUK;              // MAXBUK+1
    int*   bcur   = bbase + (MAXBUK + 1);       // MAXBUK
    size_t off = (size_t)(bcur + MAXBUK - (int*)d_ws);
    off = (off + 3) & ~(size_t)3;               // 16B align
    uint32* Wb   = (uint32*)d_ws + off;         // 2 * 2048 uints
    int*   csrs  = (int*)(Wb + 2 * 2048);       // E ints
    size_t off2 = (size_t)(csrs + E - (int*)d_ws);
    off2 = (off2 + 1) & ~(size_t)1;             // 8B align
    int2*  inter = (int2*)((int*)d_ws + off2);  // E int2

    const int T = 256;

    // CSR build: bucket hist -> scan -> run-reserved scatter -> per-bucket build
    k_zero_int<<<1, 256, 0, stream>>>(bcnt, MAXBUK);
    k_bhist<<<256, T, 0, stream>>>(dst, bcnt, E, NBUK);
    k_bscan<<<1, 64, 0, stream>>>(bcnt, bbase, bcur, NBUK);
    k_bscatter<<<128, T, 0, stream>>>(src, dst, bcur, inter, E);
    k_build<<<NBUK, T, 0, stream>>>(inter, bbase, rowptr, dinv, csrs, N, NBUK);

    // weight packing + pooled zero
    k_prepW<<<1, 64, 0, stream>>>(W1, Wb);
    k_prepW<<<1, 64, 0, stream>>>(W2, Wb + 2048);
    k_zero<<<(G * H + T - 1) / T, T, 0, stream>>>(pooled, G * H);

    const int NBG = (N + 127) / 128;

    // layer 1
    k_gemm_mfma<0><<<NBG, T, 0, stream>>>(x, Wb, dinv, bufA, N);
    k_aggregate<0><<<(N + 7) / 8, T, 0, stream>>>(bufA, csrs, rowptr, dinv, b1, batch,
                                                  bufB, pooled, N);

    // layer 2 + fused pool
    k_gemm_mfma<1><<<NBG, T, 0, stream>>>(bufB, Wb + 2048, dinv, bufA, N);
    k_aggregate<1><<<(N + 7) / 8, T, 0, stream>>>(bufA, csrs, rowptr, dinv, b2, batch,
                                                  nullptr, pooled, N);

    // head
    k_final<<<1, 128, 0, stream>>>(pooled, gf, Wlin, blin, out);
}

// Round 12
// 178.397 us; speedup vs baseline: 1.9447x; 1.0076x over previous
//
#include <hip/hip_runtime.h>

#define H 64
#define G 64
#define OUT 2
#define MAXBUK 128
#define BSHIFT 10
#define CAP 12288

typedef unsigned int uint32;
using short8 = __attribute__((ext_vector_type(8))) short;
using f32x4  = __attribute__((ext_vector_type(4))) float;

union ABFrag { uint32 u[4]; uint4 q; short8 v; };

__device__ inline float bf16lo(uint32 u) { return __uint_as_float(u << 16); }
__device__ inline float bf16hi(uint32 u) { return __uint_as_float(u & 0xffff0000u); }
__device__ inline uint32 packbf16(float a, float b) {
    uint32 ua = __float_as_uint(a);
    uint32 ub = __float_as_uint(b);
    ua = (ua + 0x7fffu + ((ua >> 16) & 1u)) >> 16;                 // RNE
    ub = (ub + 0x7fffu + ((ub >> 16) & 1u)) & 0xffff0000u;         // RNE
    return ua | ub;
}

// ---------------- zero ----------------
__global__ void k_zero_int(int* p, int n) {
    int i = blockIdx.x * blockDim.x + threadIdx.x;
    if (i < n) p[i] = 0;
}

__global__ void k_zero(float* p, int n) {
    int i = blockIdx.x * blockDim.x + threadIdx.x;
    if (i < n) p[i] = 0.0f;
}

// ---------------- bucket histogram (LDS-private, tiny merge) ----------------
__global__ __launch_bounds__(256) void k_bhist(const int* __restrict__ dst,
                                               int* __restrict__ bcnt, int e, int nbuk) {
    __shared__ int h[MAXBUK];
    for (int i = threadIdx.x; i < MAXBUK; i += 256) h[i] = 0;
    __syncthreads();
    int stride = gridDim.x * 256;
    for (int i = blockIdx.x * 256 + threadIdx.x; i < e; i += stride)
        atomicAdd(&h[__builtin_nontemporal_load(&dst[i]) >> BSHIFT], 1);
    __syncthreads();
    for (int i = threadIdx.x; i < nbuk; i += 256)
        if (h[i]) atomicAdd(&bcnt[i], h[i]);
}

// ---------------- scan bucket totals (98 values; serial is fine) ----------------
__global__ void k_bscan(const int* __restrict__ bcnt, int* __restrict__ bbase,
                        int* __restrict__ bcur, int nbuk) {
    if (threadIdx.x == 0) {
        int run = 0;
        for (int i = 0; i < nbuk; ++i) {
            bbase[i] = run; bcur[i] = run; run += bcnt[i];
        }
        bbase[nbuk] = run;
    }
}

// ---------------- bucket scatter: (src,dst) -> inter, contiguous runs ----------------
__global__ __launch_bounds__(256) void k_bscatter(const int* __restrict__ src,
                                                  const int* __restrict__ dst,
                                                  int* __restrict__ bcur,
                                                  int2* __restrict__ inter, int e) {
    __shared__ int cnt[MAXBUK];
    __shared__ int run[MAXBUK];
    int per = (e + gridDim.x - 1) / gridDim.x;
    int lo = blockIdx.x * per, hi = min(lo + per, e);
    for (int i = threadIdx.x; i < MAXBUK; i += 256) cnt[i] = 0;
    __syncthreads();
    for (int i = lo + threadIdx.x; i < hi; i += 256)
        atomicAdd(&cnt[dst[i] >> BSHIFT], 1);
    __syncthreads();
    if (threadIdx.x < MAXBUK) {
        int c = cnt[threadIdx.x];
        run[threadIdx.x] = c ? atomicAdd(&bcur[threadIdx.x], c) : 0;
        cnt[threadIdx.x] = 0;
    }
    __syncthreads();
    for (int i = lo + threadIdx.x; i < hi; i += 256) {
        int d = dst[i];
        int s = src[i];
        int b = d >> BSHIFT;
        int pos = run[b] + atomicAdd(&cnt[b], 1);
        inter[pos] = make_int2(s, d);
    }
}

// ---------------- per-bucket CSR build: rowptr + dinv + staged coalesced csr ----------------
__global__ __launch_bounds__(256) void k_build(const int2* __restrict__ inter,
                                               const int* __restrict__ bbase,
                                               int* __restrict__ rowptr,
                                               float* __restrict__ dinv,
                                               int* __restrict__ csr,
                                               int n, int nbuk) {
    __shared__ int cnt[1024];
    __shared__ int scn[1024];
    __shared__ int part[256];
    __shared__ int stage[CAP];
    int b = blockIdx.x;
    int t = threadIdx.x;
    int nlo = b << BSHIFT;
    int nhi = min(nlo + 1024, n);
    int nn = nhi - nlo;
    int e0 = bbase[b], e1 = bbase[b + 1];
    int ne = e1 - e0;
    for (int i = t; i < nn; i += 256) cnt[i] = 0;
    __syncthreads();
    for (int i = t; i < ne; i += 256)
        atomicAdd(&cnt[inter[e0 + i].y - nlo], 1);
    __syncthreads();
    // exclusive scan over nn (<=1024): 4 per thread + Hillis-Steele on partials
    int base4 = 4 * t;
    int sum = 0;
    for (int j = 0; j < 4; ++j) {
        int idx = base4 + j;
        int v = (idx < nn) ? cnt[idx] : 0;
        if (idx < nn) scn[idx] = sum;
        sum += v;
    }
    part[t] = sum;
    __syncthreads();
    for (int off = 1; off < 256; off <<= 1) {
        int v = (t >= off) ? part[t - off] : 0;
        __syncthreads();
        part[t] += v;
        __syncthreads();
    }
    int pbase = (t == 0) ? 0 : part[t - 1];
    for (int j = 0; j < 4; ++j) {
        int idx = base4 + j;
        if (idx < nn) scn[idx] += pbase;
    }
    __syncthreads();
    // rowptr + dinv (coalesced)
    for (int i = t; i < nn; i += 256) {
        rowptr[nlo + i] = e0 + scn[i];
        dinv[nlo + i] = rsqrtf((float)cnt[i] + 1.0f);
    }
    if (b == 0 && t == 0) rowptr[n] = bbase[nbuk];
    // reuse cnt as cursor
    for (int i = t; i < nn; i += 256) cnt[i] = 0;
    __syncthreads();
    // scatter into LDS stage (rare overflow -> direct global)
    for (int i = t; i < ne; i += 256) {
        int2 p = inter[e0 + i];
        int ln = p.y - nlo;
        int pos = scn[ln] + atomicAdd(&cnt[ln], 1);
        if (pos < CAP) stage[pos] = p.x;
        else csr[e0 + pos] = p.x;
    }
    __syncthreads();
    int m = min(ne, CAP);
    for (int i = t; i < m; i += 256) csr[e0 + i] = stage[i];  // coalesced
}

// ---------------- pack W into MFMA B-fragment layout (bf16) ----------------
__global__ void k_prepW(const float* __restrict__ W, uint32* __restrict__ Wb) {
    int lane = threadIdx.x;  // 64 threads
    for (int ct = 0; ct < 4; ++ct)
        for (int ks = 0; ks < 2; ++ks) {
            int col = ct * 16 + (lane & 15);
            int k0 = ks * 32 + (lane >> 4) * 8;
            int slot = ct * 2 + ks;
            for (int r = 0; r < 4; ++r) {
                float a = W[(k0 + 2 * r) * 64 + col];
                float b = W[(k0 + 2 * r + 1) * 64 + col];
                Wb[(slot * 64 + lane) * 4 + r] = packbf16(a, b);
            }
        }
}

// ---------------- MFMA GEMM: Y(bf16,[n,64]) = (X[n,64] @ W) * dinv[row] ----------------
template <int BFIN>
__global__ __launch_bounds__(256) void k_gemm_mfma(const void* __restrict__ Xv,
                                                   const uint32* __restrict__ Wb,
                                                   const float* __restrict__ dinv,
                                                   uint32* __restrict__ Y, int n) {
    int lane = threadIdx.x & 63;
    int wave = threadIdx.x >> 6;
    int l15 = lane & 15;
    int grp = lane >> 4;  // 0..3
    ABFrag bf[4][2];
    const uint4* Wb4 = (const uint4*)Wb;
#pragma unroll
    for (int ct = 0; ct < 4; ++ct)
#pragma unroll
        for (int ks = 0; ks < 2; ++ks)
            bf[ct][ks].q = Wb4[(ct * 2 + ks) * 64 + lane];

    int rbase0 = blockIdx.x * 128 + wave * 32;
    f32x4 acc[2][4] = {};
#pragma unroll
    for (int sub = 0; sub < 2; ++sub) {
        int row = min(rbase0 + sub * 16 + l15, n - 1);
        ABFrag a[2];
        if (BFIN) {
            const uint4* X4 = (const uint4*)Xv;
#pragma unroll
            for (int ks = 0; ks < 2; ++ks)
                a[ks].q = X4[(size_t)row * 8 + ks * 4 + grp];
        } else {
            const float4* X4 = (const float4*)Xv;
#pragma unroll
            for (int ks = 0; ks < 2; ++ks) {
                float4 f0 = X4[(size_t)row * 16 + ks * 8 + grp * 2];
                float4 f1 = X4[(size_t)row * 16 + ks * 8 + grp * 2 + 1];
                a[ks].u[0] = packbf16(f0.x, f0.y);
                a[ks].u[1] = packbf16(f0.z, f0.w);
                a[ks].u[2] = packbf16(f1.x, f1.y);
                a[ks].u[3] = packbf16(f1.z, f1.w);
            }
        }
#pragma unroll
        for (int ct = 0; ct < 4; ++ct) {
            acc[sub][ct] = __builtin_amdgcn_mfma_f32_16x16x32_bf16(a[0].v, bf[ct][0].v,
                                                                   acc[sub][ct], 0, 0, 0);
            acc[sub][ct] = __builtin_amdgcn_mfma_f32_16x16x32_bf16(a[1].v, bf[ct][1].v,
                                                                   acc[sub][ct], 0, 0, 0);
        }
    }
#pragma unroll
    for (int sub = 0; sub < 2; ++sub) {
        int rb = rbase0 + sub * 16;
#pragma unroll
        for (int r = 0; r < 4; ++r) {
            int row = rb + grp * 4 + r;
            float dd = dinv[min(row, n - 1)];
#pragma unroll
            for (int ct = 0; ct < 4; ++ct) {
                float v = acc[sub][ct][r] * dd;
                float w = __shfl_xor(v, 1);
                if (!(lane & 1) && row < n)
                    Y[(size_t)row * 32 + ct * 8 + (l15 >> 1)] = packbf16(v, w);
            }
        }
    }
}

// ---------------- fused aggregate: out = relu(dinv_d*(hs_d + sum hs_src) + b) ----------------
// one node per HALF-wave; clamped unroll-8 -> 8 gathers in flight per chain
template <int DOPOOL>
__global__ __launch_bounds__(256) void k_aggregate(const uint32* __restrict__ h,
                                                   const int* __restrict__ csrs,
                                                   const int* __restrict__ rowptr,
                                                   const float* __restrict__ dinv,
                                                   const float* __restrict__ b,
                                                   const int* __restrict__ batch,
                                                   uint32* __restrict__ hout,
                                                   float* __restrict__ pooled, int n) {
    __shared__ float red[8][64];
    __shared__ int sg[8];
    int tid = threadIdx.x;
    int wave = tid >> 6;
    int lane = tid & 63;
    int half = lane >> 5;
    int hl = lane & 31;
    int slot = wave * 2 + half;
    int node = blockIdx.x * 8 + slot;
    bool active = node < n;
    float o0 = 0.f, o1 = 0.f;
    if (active) {
        int r0 = __builtin_nontemporal_load(&rowptr[node]);
        int r1 = __builtin_nontemporal_load(&rowptr[node + 1]);
        uint32 sv = h[(size_t)node * 32 + hl];
        float acc0 = bf16lo(sv);
        float acc1 = bf16hi(sv);
        int m = r1 - 1;
        for (int e = r0; e < r1; e += 8) {
            int e1 = min(e + 1, m);
            int e2 = min(e + 2, m);
            int e3 = min(e + 3, m);
            int e4 = min(e + 4, m);
            int e5 = min(e + 5, m);
            int e6 = min(e + 6, m);
            int e7 = min(e + 7, m);
            int s0 = __builtin_nontemporal_load(&csrs[e]);
            int s1 = __builtin_nontemporal_load(&csrs[e1]);
            int s2 = __builtin_nontemporal_load(&csrs[e2]);
            int s3 = __builtin_nontemporal_load(&csrs[e3]);
            int s4 = __builtin_nontemporal_load(&csrs[e4]);
            int s5 = __builtin_nontemporal_load(&csrs[e5]);
            int s6 = __builtin_nontemporal_load(&csrs[e6]);
            int s7 = __builtin_nontemporal_load(&csrs[e7]);
            uint32 g0 = h[(size_t)s0 * 32 + hl];
            uint32 g1 = h[(size_t)s1 * 32 + hl];
            uint32 g2 = h[(size_t)s2 * 32 + hl];
            uint32 g3 = h[(size_t)s3 * 32 + hl];
            uint32 g4 = h[(size_t)s4 * 32 + hl];
            uint32 g5 = h[(size_t)s5 * 32 + hl];
            uint32 g6 = h[(size_t)s6 * 32 + hl];
            uint32 g7 = h[(size_t)s7 * 32 + hl];
            if (e + 1 > m) g1 = 0u;
            if (e + 2 > m) g2 = 0u;
            if (e + 3 > m) g3 = 0u;
            if (e + 4 > m) g4 = 0u;
            if (e + 5 > m) g5 = 0u;
            if (e + 6 > m) g6 = 0u;
            if (e + 7 > m) g7 = 0u;
            acc0 += (bf16lo(g0) + bf16lo(g1)) + (bf16lo(g2) + bf16lo(g3)) +
                    (bf16lo(g4) + bf16lo(g5)) + (bf16lo(g6) + bf16lo(g7));
            acc1 += (bf16hi(g0) + bf16hi(g1)) + (bf16hi(g2) + bf16hi(g3)) +
                    (bf16hi(g4) + bf16hi(g5)) + (bf16hi(g6) + bf16hi(g7));
        }
        float dd = dinv[node];
        o0 = acc0 * dd + b[2 * hl + 0];
        o1 = acc1 * dd + b[2 * hl + 1];
        o0 = o0 > 0.f ? o0 : 0.f;
        o1 = o1 > 0.f ? o1 : 0.f;
        if (!DOPOOL) hout[(size_t)node * 32 + hl] = packbf16(o0, o1);
    }
    if (DOPOOL) {
        red[slot][2 * hl + 0] = active ? o0 : 0.f;
        red[slot][2 * hl + 1] = active ? o1 : 0.f;
        if (hl == 0) sg[slot] = active ? batch[node] : -1;
        __syncthreads();
        if (wave == 0) {
            float s = red[0][lane];
            int gcur = sg[0];
            for (int w = 1; w < 8; ++w) {
                int gw = sg[w];
                if (gw < 0) break;
                if (gw == gcur) {
                    s += red[w][lane];
                } else {
                    if (gcur >= 0) atomicAdd(&pooled[gcur * H + lane], s);
                    s = red[w][lane];
                    gcur = gw;
                }
            }
            if (gcur >= 0) atomicAdd(&pooled[gcur * H + lane], s);
        }
    }
}

// ---------------- final linear ----------------
__global__ void k_final(const float* __restrict__ pooled, const float* __restrict__ gf,
                        const float* __restrict__ Wlin, const float* __restrict__ blin,
                        float* __restrict__ out) {
    int t = threadIdx.x;
    if (t >= G * OUT) return;
    int g = t >> 1, o = t & 1;
    float acc = blin[o];
#pragma unroll
    for (int j = 0; j < 64; ++j) acc += pooled[g * H + j] * Wlin[j * OUT + o];
    acc += gf[g] * Wlin[64 * OUT + o];
    out[g * OUT + o] = acc;
}

extern "C" void kernel_launch(void* const* d_in, const int* in_sizes, int n_in,
                              void* d_out, int out_size, void* d_ws, size_t ws_size,
                              hipStream_t stream) {
    const float* x          = (const float*)d_in[0];
    const int*   edge_index = (const int*)d_in[1];
    const int*   batch      = (const int*)d_in[2];
    const float* gf         = (const float*)d_in[3];
    const float* W1         = (const float*)d_in[4];
    const float* b1         = (const float*)d_in[5];
    const float* W2         = (const float*)d_in[6];
    const float* b2         = (const float*)d_in[7];
    const float* Wlin       = (const float*)d_in[8];
    const float* blin       = (const float*)d_in[9];
    float* out = (float*)d_out;

    const int N = in_sizes[0] / H;
    const int E = in_sizes[1] / 2;
    const int* src = edge_index;
    const int* dst = edge_index + E;
    const int NBUK = (N + (1 << BSHIFT) - 1) >> BSHIFT;  // 98 for N=100k (<=MAXBUK)

    // workspace layout
    float* ws = (float*)d_ws;
    float* dinv   = ws;                         // N
    uint32* bufA  = (uint32*)(dinv + N);        // N*32 uints (bf16 packed)
    uint32* bufB  = bufA + (size_t)N * 32;      // N*32 uints
    float* pooled = (float*)(bufB + (size_t)N * 32);  // G*H
    int*   rowptr = (int*)(pooled + G * H);     // N+1
    int*   bcnt   = rowptr + (N + 1);           // MAXBUK
    int*   bbase  = bcnt + MAXBUK;              // MAXBUK+1
    int*   bcur   = bbase + (MAXBUK + 1);       // MAXBUK
    size_t off = (size_t)(bcur + MAXBUK - (int*)d_ws);
    off = (off + 3) & ~(size_t)3;               // 16B align
    uint32* Wb   = (uint32*)d_ws + off;         // 2 * 2048 uints
    int*   csrs  = (int*)(Wb + 2 * 2048);       // E ints
    size_t off2 = (size_t)(csrs + E - (int*)d_ws);
    off2 = (off2 + 1) & ~(size_t)1;             // 8B align
    int2*  inter = (int2*)((int*)d_ws + off2);  // E int2

    const int T = 256;

    // CSR build: bucket hist -> scan -> run-reserved scatter -> per-bucket build
    k_zero_int<<<1, 256, 0, stream>>>(bcnt, MAXBUK);
    k_bhist<<<256, T, 0, stream>>>(dst, bcnt, E, NBUK);
    k_bscan<<<1, 64, 0, stream>>>(bcnt, bbase, bcur, NBUK);
    k_bscatter<<<128, T, 0, stream>>>(src, dst, bcur, inter, E);
    k_build<<<NBUK, T, 0, stream>>>(inter, bbase, rowptr, dinv, csrs, N, NBUK);

    // weight packing + pooled zero
    k_prepW<<<1, 64, 0, stream>>>(W1, Wb);
    k_prepW<<<1, 64, 0, stream>>>(W2, Wb + 2048);
    k_zero<<<(G * H + T - 1) / T, T, 0, stream>>>(pooled, G * H);

    const int NBG = (N + 127) / 128;

    // layer 1
    k_gemm_mfma<0><<<NBG, T, 0, stream>>>(x, Wb, dinv, bufA, N);
    k_aggregate<0><<<(N + 7) / 8, T, 0, stream>>>(bufA, csrs, rowptr, dinv, b1, batch,
                                                  bufB, pooled, N);

    // layer 2 + fused pool
    k_gemm_mfma<1><<<NBG, T, 0, stream>>>(bufB, Wb + 2048, dinv, bufA, N);
    k_aggregate<1><<<(N + 7) / 8, T, 0, stream>>>(bufA, csrs, rowptr, dinv, b2, batch,
                                                  nullptr, pooled, N);

    // head
    k_final<<<1, 128, 0, stream>>>(pooled, gf, Wlin, blin, out);
}

// Round 13
// 175.586 us; speedup vs baseline: 1.9759x; 1.0160x over previous
//
#include <hip/hip_runtime.h>

#define H 64
#define G 64
#define OUT 2
#define MAXBUK 128
#define BSHIFT 10
#define CAP 12288

typedef unsigned int uint32;
using short8 = __attribute__((ext_vector_type(8))) short;
using f32x4  = __attribute__((ext_vector_type(4))) float;

union ABFrag { uint32 u[4]; uint4 q; short8 v; };

__device__ inline float bf16lo(uint32 u) { return __uint_as_float(u << 16); }
__device__ inline float bf16hi(uint32 u) { return __uint_as_float(u & 0xffff0000u); }
__device__ inline uint32 packbf16(float a, float b) {
    uint32 ua = __float_as_uint(a);
    uint32 ub = __float_as_uint(b);
    ua = (ua + 0x7fffu + ((ua >> 16) & 1u)) >> 16;                 // RNE
    ub = (ub + 0x7fffu + ((ub >> 16) & 1u)) & 0xffff0000u;         // RNE
    return ua | ub;
}

// ---------------- fused setup: prepW(W1), prepW(W2), zero pooled + bcnt ----------------
// W B-frag layout for mfma_16x16x32_bf16: entry i=(slot*64+lane)*4+r,
// slot=ct*2+ks: Wb[i] = pack(W[k0+2r][col], W[k0+2r+1][col]), col=ct*16+(lane&15),
// k0=ks*32+(lane>>4)*8
__global__ __launch_bounds__(256) void k_setup(const float* __restrict__ W1,
                                               const float* __restrict__ W2,
                                               uint32* __restrict__ Wb,
                                               float* __restrict__ pooled,
                                               int* __restrict__ bcnt) {
    int blk = blockIdx.x;
    int t = threadIdx.x;
    if (blk < 2) {
        const float* W = blk ? W2 : W1;
        uint32* dw = Wb + blk * 2048;
        for (int i = t; i < 2048; i += 256) {
            int r = i & 3;
            int lane = (i >> 2) & 63;
            int slot = i >> 8;
            int ct = slot >> 1, ks = slot & 1;
            int col = ct * 16 + (lane & 15);
            int k0 = ks * 32 + (lane >> 4) * 8;
            float a = W[(k0 + 2 * r) * 64 + col];
            float b = W[(k0 + 2 * r + 1) * 64 + col];
            dw[i] = packbf16(a, b);
        }
    } else {
        for (int i = t; i < G * H; i += 256) pooled[i] = 0.0f;
        if (t < MAXBUK) bcnt[t] = 0;
    }
}

// ---------------- bucket histogram (LDS-private, tiny merge) ----------------
__global__ __launch_bounds__(256) void k_bhist(const int* __restrict__ dst,
                                               int* __restrict__ bcnt, int e, int nbuk) {
    __shared__ int h[MAXBUK];
    for (int i = threadIdx.x; i < MAXBUK; i += 256) h[i] = 0;
    __syncthreads();
    int stride = gridDim.x * 256;
    for (int i = blockIdx.x * 256 + threadIdx.x; i < e; i += stride)
        atomicAdd(&h[__builtin_nontemporal_load(&dst[i]) >> BSHIFT], 1);
    __syncthreads();
    for (int i = threadIdx.x; i < nbuk; i += 256)
        if (h[i]) atomicAdd(&bcnt[i], h[i]);
}

// ---------------- scan bucket totals (98 values; serial is fine) ----------------
__global__ void k_bscan(const int* __restrict__ bcnt, int* __restrict__ bbase,
                        int* __restrict__ bcur, int nbuk) {
    if (threadIdx.x == 0) {
        int run = 0;
        for (int i = 0; i < nbuk; ++i) {
            bbase[i] = run; bcur[i] = run; run += bcnt[i];
        }
        bbase[nbuk] = run;
    }
}

// ---------------- bucket scatter: (src,dst) -> inter, contiguous runs ----------------
__global__ __launch_bounds__(256) void k_bscatter(const int* __restrict__ src,
                                                  const int* __restrict__ dst,
                                                  int* __restrict__ bcur,
                                                  int2* __restrict__ inter, int e) {
    __shared__ int cnt[MAXBUK];
    __shared__ int run[MAXBUK];
    int per = (e + gridDim.x - 1) / gridDim.x;
    int lo = blockIdx.x * per, hi = min(lo + per, e);
    for (int i = threadIdx.x; i < MAXBUK; i += 256) cnt[i] = 0;
    __syncthreads();
    for (int i = lo + threadIdx.x; i < hi; i += 256)
        atomicAdd(&cnt[dst[i] >> BSHIFT], 1);
    __syncthreads();
    if (threadIdx.x < MAXBUK) {
        int c = cnt[threadIdx.x];
        run[threadIdx.x] = c ? atomicAdd(&bcur[threadIdx.x], c) : 0;
        cnt[threadIdx.x] = 0;
    }
    __syncthreads();
    for (int i = lo + threadIdx.x; i < hi; i += 256) {
        int d = dst[i];
        int s = src[i];
        int b = d >> BSHIFT;
        int pos = run[b] + atomicAdd(&cnt[b], 1);
        inter[pos] = make_int2(s, d);
    }
}

// ---------------- per-bucket CSR build: rowptr + dinv + staged coalesced csr ----------------
__global__ __launch_bounds__(256) void k_build(const int2* __restrict__ inter,
                                               const int* __restrict__ bbase,
                                               int* __restrict__ rowptr,
                                               float* __restrict__ dinv,
                                               int* __restrict__ csr,
                                               int n, int nbuk) {
    __shared__ int cnt[1024];
    __shared__ int scn[1024];
    __shared__ int part[256];
    __shared__ int stage[CAP];
    int b = blockIdx.x;
    int t = threadIdx.x;
    int nlo = b << BSHIFT;
    int nhi = min(nlo + 1024, n);
    int nn = nhi - nlo;
    int e0 = bbase[b], e1 = bbase[b + 1];
    int ne = e1 - e0;
    for (int i = t; i < nn; i += 256) cnt[i] = 0;
    __syncthreads();
    for (int i = t; i < ne; i += 256)
        atomicAdd(&cnt[inter[e0 + i].y - nlo], 1);
    __syncthreads();
    int base4 = 4 * t;
    int sum = 0;
    for (int j = 0; j < 4; ++j) {
        int idx = base4 + j;
        int v = (idx < nn) ? cnt[idx] : 0;
        if (idx < nn) scn[idx] = sum;
        sum += v;
    }
    part[t] = sum;
    __syncthreads();
    for (int off = 1; off < 256; off <<= 1) {
        int v = (t >= off) ? part[t - off] : 0;
        __syncthreads();
        part[t] += v;
        __syncthreads();
    }
    int pbase = (t == 0) ? 0 : part[t - 1];
    for (int j = 0; j < 4; ++j) {
        int idx = base4 + j;
        if (idx < nn) scn[idx] += pbase;
    }
    __syncthreads();
    for (int i = t; i < nn; i += 256) {
        rowptr[nlo + i] = e0 + scn[i];
        dinv[nlo + i] = rsqrtf((float)cnt[i] + 1.0f);
    }
    if (b == 0 && t == 0) rowptr[n] = bbase[nbuk];
    for (int i = t; i < nn; i += 256) cnt[i] = 0;
    __syncthreads();
    for (int i = t; i < ne; i += 256) {
        int2 p = inter[e0 + i];
        int ln = p.y - nlo;
        int pos = scn[ln] + atomicAdd(&cnt[ln], 1);
        if (pos < CAP) stage[pos] = p.x;
        else csr[e0 + pos] = p.x;
    }
    __syncthreads();
    int m = min(ne, CAP);
    for (int i = t; i < m; i += 256) csr[e0 + i] = stage[i];  // coalesced
}

// ---------------- MFMA GEMM: Y(bf16,[n,64]) = (X[n,64] @ W) * dinv[row] ----------------
template <int BFIN>
__global__ __launch_bounds__(256) void k_gemm_mfma(const void* __restrict__ Xv,
                                                   const uint32* __restrict__ Wb,
                                                   const float* __restrict__ dinv,
                                                   uint32* __restrict__ Y, int n) {
    int lane = threadIdx.x & 63;
    int wave = threadIdx.x >> 6;
    int l15 = lane & 15;
    int grp = lane >> 4;  // 0..3
    ABFrag bf[4][2];
    const uint4* Wb4 = (const uint4*)Wb;
#pragma unroll
    for (int ct = 0; ct < 4; ++ct)
#pragma unroll
        for (int ks = 0; ks < 2; ++ks)
            bf[ct][ks].q = Wb4[(ct * 2 + ks) * 64 + lane];

    int rbase0 = blockIdx.x * 128 + wave * 32;
    f32x4 acc[2][4] = {};
#pragma unroll
    for (int sub = 0; sub < 2; ++sub) {
        int row = min(rbase0 + sub * 16 + l15, n - 1);
        ABFrag a[2];
        if (BFIN) {
            const uint4* X4 = (const uint4*)Xv;
#pragma unroll
            for (int ks = 0; ks < 2; ++ks)
                a[ks].q = X4[(size_t)row * 8 + ks * 4 + grp];
        } else {
            const float4* X4 = (const float4*)Xv;
#pragma unroll
            for (int ks = 0; ks < 2; ++ks) {
                float4 f0 = X4[(size_t)row * 16 + ks * 8 + grp * 2];
                float4 f1 = X4[(size_t)row * 16 + ks * 8 + grp * 2 + 1];
                a[ks].u[0] = packbf16(f0.x, f0.y);
                a[ks].u[1] = packbf16(f0.z, f0.w);
                a[ks].u[2] = packbf16(f1.x, f1.y);
                a[ks].u[3] = packbf16(f1.z, f1.w);
            }
        }
#pragma unroll
        for (int ct = 0; ct < 4; ++ct) {
            acc[sub][ct] = __builtin_amdgcn_mfma_f32_16x16x32_bf16(a[0].v, bf[ct][0].v,
                                                                   acc[sub][ct], 0, 0, 0);
            acc[sub][ct] = __builtin_amdgcn_mfma_f32_16x16x32_bf16(a[1].v, bf[ct][1].v,
                                                                   acc[sub][ct], 0, 0, 0);
        }
    }
#pragma unroll
    for (int sub = 0; sub < 2; ++sub) {
        int rb = rbase0 + sub * 16;
#pragma unroll
        for (int r = 0; r < 4; ++r) {
            int row = rb + grp * 4 + r;
            float dd = dinv[min(row, n - 1)];
#pragma unroll
            for (int ct = 0; ct < 4; ++ct) {
                float v = acc[sub][ct][r] * dd;
                float w = __shfl_xor(v, 1);
                if (!(lane & 1) && row < n)
                    Y[(size_t)row * 32 + ct * 8 + (l15 >> 1)] = packbf16(v, w);
            }
        }
    }
}

// ---------------- fused aggregate: out = relu(dinv_d*(hs_d + sum hs_src) + b) ----------------
// one node per HALF-wave; batch-16: all 16 index loads issue at once, then 16
// predicated gathers -> 3 dependent memory rounds per node (97% of nodes).
template <int DOPOOL>
__global__ __launch_bounds__(256) void k_aggregate(const uint32* __restrict__ h,
                                                   const int* __restrict__ csrs,
                                                   const int* __restrict__ rowptr,
                                                   const float* __restrict__ dinv,
                                                   const float* __restrict__ b,
                                                   const int* __restrict__ batch,
                                                   uint32* __restrict__ hout,
                                                   float* __restrict__ pooled, int n) {
    __shared__ float red[8][64];
    __shared__ int sg[8];
    int tid = threadIdx.x;
    int wave = tid >> 6;
    int lane = tid & 63;
    int half = lane >> 5;
    int hl = lane & 31;
    int slot = wave * 2 + half;
    int node = blockIdx.x * 8 + slot;
    bool active = node < n;
    float o0 = 0.f, o1 = 0.f;
    if (active) {
        int r0 = rowptr[node];
        int r1 = rowptr[node + 1];
        int m = r1 - 1;
        int mc = max(m, 0);  // safe clamp (deg==0 at r0==0)
        uint32 sv = h[(size_t)node * 32 + hl];
        float acc0 = bf16lo(sv);
        float acc1 = bf16hi(sv);
        // batch-16: independent index loads
        int s[16];
#pragma unroll
        for (int j = 0; j < 16; ++j)
            s[j] = __builtin_nontemporal_load(&csrs[min(r0 + j, mc)]);
        // predicated gathers (masked lanes issue no transaction)
        uint32 g[16];
#pragma unroll
        for (int j = 0; j < 16; ++j)
            g[j] = (r0 + j <= m) ? h[(size_t)s[j] * 32 + hl] : 0u;
#pragma unroll
        for (int j = 0; j < 16; ++j) {
            acc0 += bf16lo(g[j]);
            acc1 += bf16hi(g[j]);
        }
        // rare overflow: degree > 16
        for (int e = r0 + 16; e < r1; e += 8) {
            int t1 = min(e + 1, m), t2 = min(e + 2, m), t3 = min(e + 3, m);
            int t4 = min(e + 4, m), t5 = min(e + 5, m), t6 = min(e + 6, m);
            int t7 = min(e + 7, m);
            int u0 = csrs[e],  u1 = csrs[t1], u2 = csrs[t2], u3 = csrs[t3];
            int u4 = csrs[t4], u5 = csrs[t5], u6 = csrs[t6], u7 = csrs[t7];
            uint32 q0 = h[(size_t)u0 * 32 + hl];
            uint32 q1 = (e + 1 <= m) ? h[(size_t)u1 * 32 + hl] : 0u;
            uint32 q2 = (e + 2 <= m) ? h[(size_t)u2 * 32 + hl] : 0u;
            uint32 q3 = (e + 3 <= m) ? h[(size_t)u3 * 32 + hl] : 0u;
            uint32 q4 = (e + 4 <= m) ? h[(size_t)u4 * 32 + hl] : 0u;
            uint32 q5 = (e + 5 <= m) ? h[(size_t)u5 * 32 + hl] : 0u;
            uint32 q6 = (e + 6 <= m) ? h[(size_t)u6 * 32 + hl] : 0u;
            uint32 q7 = (e + 7 <= m) ? h[(size_t)u7 * 32 + hl] : 0u;
            acc0 += (bf16lo(q0) + bf16lo(q1)) + (bf16lo(q2) + bf16lo(q3)) +
                    (bf16lo(q4) + bf16lo(q5)) + (bf16lo(q6) + bf16lo(q7));
            acc1 += (bf16hi(q0) + bf16hi(q1)) + (bf16hi(q2) + bf16hi(q3)) +
                    (bf16hi(q4) + bf16hi(q5)) + (bf16hi(q6) + bf16hi(q7));
        }
        float dd = dinv[node];
        o0 = acc0 * dd + b[2 * hl + 0];
        o1 = acc1 * dd + b[2 * hl + 1];
        o0 = o0 > 0.f ? o0 : 0.f;
        o1 = o1 > 0.f ? o1 : 0.f;
        if (!DOPOOL) hout[(size_t)node * 32 + hl] = packbf16(o0, o1);
    }
    if (DOPOOL) {
        red[slot][2 * hl + 0] = active ? o0 : 0.f;
        red[slot][2 * hl + 1] = active ? o1 : 0.f;
        if (hl == 0) sg[slot] = active ? batch[node] : -1;
        __syncthreads();
        if (wave == 0) {
            float s = red[0][lane];
            int gcur = sg[0];
            for (int w = 1; w < 8; ++w) {
                int gw = sg[w];
                if (gw < 0) break;
                if (gw == gcur) {
                    s += red[w][lane];
                } else {
                    if (gcur >= 0) atomicAdd(&pooled[gcur * H + lane], s);
                    s = red[w][lane];
                    gcur = gw;
                }
            }
            if (gcur >= 0) atomicAdd(&pooled[gcur * H + lane], s);
        }
    }
}

// ---------------- final linear ----------------
__global__ void k_final(const float* __restrict__ pooled, const float* __restrict__ gf,
                        const float* __restrict__ Wlin, const float* __restrict__ blin,
                        float* __restrict__ out) {
    int t = threadIdx.x;
    if (t >= G * OUT) return;
    int g = t >> 1, o = t & 1;
    float acc = blin[o];
#pragma unroll
    for (int j = 0; j < 64; ++j) acc += pooled[g * H + j] * Wlin[j * OUT + o];
    acc += gf[g] * Wlin[64 * OUT + o];
    out[g * OUT + o] = acc;
}

extern "C" void kernel_launch(void* const* d_in, const int* in_sizes, int n_in,
                              void* d_out, int out_size, void* d_ws, size_t ws_size,
                              hipStream_t stream) {
    const float* x          = (const float*)d_in[0];
    const int*   edge_index = (const int*)d_in[1];
    const int*   batch      = (const int*)d_in[2];
    const float* gf         = (const float*)d_in[3];
    const float* W1         = (const float*)d_in[4];
    const float* b1         = (const float*)d_in[5];
    const float* W2         = (const float*)d_in[6];
    const float* b2         = (const float*)d_in[7];
    const float* Wlin       = (const float*)d_in[8];
    const float* blin       = (const float*)d_in[9];
    float* out = (float*)d_out;

    const int N = in_sizes[0] / H;
    const int E = in_sizes[1] / 2;
    const int* src = edge_index;
    const int* dst = edge_index + E;
    const int NBUK = (N + (1 << BSHIFT) - 1) >> BSHIFT;  // 98 for N=100k (<=MAXBUK)

    // workspace layout
    float* ws = (float*)d_ws;
    float* dinv   = ws;                         // N
    uint32* bufA  = (uint32*)(dinv + N);        // N*32 uints (bf16 packed)
    uint32* bufB  = bufA + (size_t)N * 32;      // N*32 uints
    float* pooled = (float*)(bufB + (size_t)N * 32);  // G*H
    int*   rowptr = (int*)(pooled + G * H);     // N+1
    int*   bcnt   = rowptr + (N + 1);           // MAXBUK
    int*   bbase  = bcnt + MAXBUK;              // MAXBUK+1
    int*   bcur   = bbase + (MAXBUK + 1);       // MAXBUK
    size_t off = (size_t)(bcur + MAXBUK - (int*)d_ws);
    off = (off + 3) & ~(size_t)3;               // 16B align
    uint32* Wb   = (uint32*)d_ws + off;         // 2 * 2048 uints
    int*   csrs  = (int*)(Wb + 2 * 2048);       // E ints
    size_t off2 = (size_t)(csrs + E - (int*)d_ws);
    off2 = (off2 + 1) & ~(size_t)1;             // 8B align
    int2*  inter = (int2*)((int*)d_ws + off2);  // E int2

    const int T = 256;

    // setup (W packs, pooled zero, bcnt zero) + CSR build
    k_setup<<<3, T, 0, stream>>>(W1, W2, Wb, pooled, bcnt);
    k_bhist<<<256, T, 0, stream>>>(dst, bcnt, E, NBUK);
    k_bscan<<<1, 64, 0, stream>>>(bcnt, bbase, bcur, NBUK);
    k_bscatter<<<128, T, 0, stream>>>(src, dst, bcur, inter, E);
    k_build<<<NBUK, T, 0, stream>>>(inter, bbase, rowptr, dinv, csrs, N, NBUK);

    const int NBG = (N + 127) / 128;

    // layer 1
    k_gemm_mfma<0><<<NBG, T, 0, stream>>>(x, Wb, dinv, bufA, N);
    k_aggregate<0><<<(N + 7) / 8, T, 0, stream>>>(bufA, csrs, rowptr, dinv, b1, batch,
                                                  bufB, pooled, N);

    // layer 2 + fused pool
    k_gemm_mfma<1><<<NBG, T, 0, stream>>>(bufB, Wb + 2048, dinv, bufA, N);
    k_aggregate<1><<<(N + 7) / 8, T, 0, stream>>>(bufA, csrs, rowptr, dinv, b2, batch,
                                                  nullptr, pooled, N);

    // head
    k_final<<<1, 128, 0, stream>>>(pooled, gf, Wlin, blin, out);
}

// Round 14
// 168.672 us; speedup vs baseline: 2.0569x; 1.0410x over previous
//
#include <hip/hip_runtime.h>

#define H 64
#define G 64
#define OUT 2
#define MAXBUK 128
#define BSHIFT 10
#define CAP 12288

typedef unsigned int uint32;
using short8 = __attribute__((ext_vector_type(8))) short;
using f32x4  = __attribute__((ext_vector_type(4))) float;

union ABFrag { uint32 u[4]; uint4 q; short8 v; };

__device__ inline float bf16lo(uint32 u) { return __uint_as_float(u << 16); }
__device__ inline float bf16hi(uint32 u) { return __uint_as_float(u & 0xffff0000u); }
__device__ inline uint32 packbf16(float a, float b) {
    uint32 ua = __float_as_uint(a);
    uint32 ub = __float_as_uint(b);
    ua = (ua + 0x7fffu + ((ua >> 16) & 1u)) >> 16;                 // RNE
    ub = (ub + 0x7fffu + ((ub >> 16) & 1u)) & 0xffff0000u;         // RNE
    return ua | ub;
}

// ---------------- fused setup: prepW(W1,W2) + zero pooled/bcnt/done ----------------
__global__ __launch_bounds__(256) void k_setup(const float* __restrict__ W1,
                                               const float* __restrict__ W2,
                                               uint32* __restrict__ Wb,
                                               float* __restrict__ pooled,
                                               int* __restrict__ bcnt,
                                               int* __restrict__ done) {
    int blk = blockIdx.x;
    int t = threadIdx.x;
    if (blk < 2) {
        const float* W = blk ? W2 : W1;
        uint32* dw = Wb + blk * 2048;
        for (int i = t; i < 2048; i += 256) {
            int r = i & 3;
            int lane = (i >> 2) & 63;
            int slot = i >> 8;
            int ct = slot >> 1, ks = slot & 1;
            int col = ct * 16 + (lane & 15);
            int k0 = ks * 32 + (lane >> 4) * 8;
            float a = W[(k0 + 2 * r) * 64 + col];
            float b = W[(k0 + 2 * r + 1) * 64 + col];
            dw[i] = packbf16(a, b);
        }
    } else {
        for (int i = t; i < G * H; i += 256) pooled[i] = 0.0f;
        if (t < MAXBUK) bcnt[t] = 0;
        if (t == 0) *done = 0;
    }
}

// ---------------- bucket histogram + fused last-block scan ----------------
__global__ __launch_bounds__(256) void k_bhist(const int* __restrict__ dst,
                                               int* __restrict__ bcnt,
                                               int* __restrict__ bbase,
                                               int* __restrict__ bcur,
                                               int* __restrict__ done,
                                               int e, int nbuk) {
    __shared__ int hh[MAXBUK];
    for (int i = threadIdx.x; i < MAXBUK; i += 256) hh[i] = 0;
    __syncthreads();
    int stride = gridDim.x * 256;
    for (int i = blockIdx.x * 256 + threadIdx.x; i < e; i += stride)
        atomicAdd(&hh[__builtin_nontemporal_load(&dst[i]) >> BSHIFT], 1);
    __syncthreads();
    for (int i = threadIdx.x; i < nbuk; i += 256)
        if (hh[i]) atomicAdd(&bcnt[i], hh[i]);
    // last finishing block performs the (tiny) serial scan
    if (threadIdx.x == 0) {
        __threadfence();
        int ticket = atomicAdd(done, 1);
        if (ticket == (int)gridDim.x - 1) {
            int run = 0;
            for (int i = 0; i < nbuk; ++i) {
                int c = atomicAdd(&bcnt[i], 0);  // coherent read
                bbase[i] = run; bcur[i] = run; run += c;
            }
            bbase[nbuk] = run;
        }
    }
}

// ---------------- bucket scatter: packed (ln<<17|src) -> inter, contiguous runs ----------------
__global__ __launch_bounds__(256) void k_bscatter(const int* __restrict__ src,
                                                  const int* __restrict__ dst,
                                                  int* __restrict__ bcur,
                                                  uint32* __restrict__ inter, int e) {
    __shared__ int cnt[MAXBUK];
    __shared__ int run[MAXBUK];
    int per = (e + gridDim.x - 1) / gridDim.x;
    int lo = blockIdx.x * per, hi = min(lo + per, e);
    for (int i = threadIdx.x; i < MAXBUK; i += 256) cnt[i] = 0;
    __syncthreads();
    for (int i = lo + threadIdx.x; i < hi; i += 256)
        atomicAdd(&cnt[dst[i] >> BSHIFT], 1);
    __syncthreads();
    if (threadIdx.x < MAXBUK) {
        int c = cnt[threadIdx.x];
        run[threadIdx.x] = c ? atomicAdd(&bcur[threadIdx.x], c) : 0;
        cnt[threadIdx.x] = 0;
    }
    __syncthreads();
    for (int i = lo + threadIdx.x; i < hi; i += 256) {
        int d = dst[i];
        int s = src[i];
        int b = d >> BSHIFT;
        int ln = d & ((1 << BSHIFT) - 1);
        int pos = run[b] + atomicAdd(&cnt[b], 1);
        inter[pos] = ((uint32)ln << 17) | (uint32)s;
    }
}

// ---------------- per-bucket CSR build ----------------
__global__ __launch_bounds__(256) void k_build(const uint32* __restrict__ inter,
                                               const int* __restrict__ bbase,
                                               int* __restrict__ rowptr,
                                               float* __restrict__ dinv,
                                               int* __restrict__ csr,
                                               int n, int nbuk) {
    __shared__ int cnt[1024];
    __shared__ int scn[1024];
    __shared__ int part[256];
    __shared__ int stage[CAP];
    int b = blockIdx.x;
    int t = threadIdx.x;
    int nlo = b << BSHIFT;
    int nhi = min(nlo + 1024, n);
    int nn = nhi - nlo;
    int e0 = bbase[b], e1 = bbase[b + 1];
    int ne = e1 - e0;
    for (int i = t; i < nn; i += 256) cnt[i] = 0;
    __syncthreads();
    for (int i = t; i < ne; i += 256)
        atomicAdd(&cnt[inter[e0 + i] >> 17], 1);
    __syncthreads();
    int base4 = 4 * t;
    int sum = 0;
    for (int j = 0; j < 4; ++j) {
        int idx = base4 + j;
        int v = (idx < nn) ? cnt[idx] : 0;
        if (idx < nn) scn[idx] = sum;
        sum += v;
    }
    part[t] = sum;
    __syncthreads();
    for (int off = 1; off < 256; off <<= 1) {
        int v = (t >= off) ? part[t - off] : 0;
        __syncthreads();
        part[t] += v;
        __syncthreads();
    }
    int pbase = (t == 0) ? 0 : part[t - 1];
    for (int j = 0; j < 4; ++j) {
        int idx = base4 + j;
        if (idx < nn) scn[idx] += pbase;
    }
    __syncthreads();
    for (int i = t; i < nn; i += 256) {
        rowptr[nlo + i] = e0 + scn[i];
        dinv[nlo + i] = rsqrtf((float)cnt[i] + 1.0f);
    }
    if (b == 0 && t == 0) rowptr[n] = bbase[nbuk];
    for (int i = t; i < nn; i += 256) cnt[i] = 0;
    __syncthreads();
    for (int i = t; i < ne; i += 256) {
        uint32 p = inter[e0 + i];
        int ln = p >> 17;
        int s = p & 0x1FFFF;
        int pos = scn[ln] + atomicAdd(&cnt[ln], 1);
        if (pos < CAP) stage[pos] = s;
        else csr[e0 + pos] = s;
    }
    __syncthreads();
    int m = min(ne, CAP);
    for (int i = t; i < m; i += 256) csr[e0 + i] = stage[i];  // coalesced
}

// ---------------- MFMA GEMM: Y(bf16,[n,64]) = (X[n,64] @ W) * dinv[row] ----------------
template <int BFIN>
__global__ __launch_bounds__(256) void k_gemm_mfma(const void* __restrict__ Xv,
                                                   const uint32* __restrict__ Wb,
                                                   const float* __restrict__ dinv,
                                                   uint32* __restrict__ Y, int n) {
    int lane = threadIdx.x & 63;
    int wave = threadIdx.x >> 6;
    int l15 = lane & 15;
    int grp = lane >> 4;  // 0..3
    ABFrag bf[4][2];
    const uint4* Wb4 = (const uint4*)Wb;
#pragma unroll
    for (int ct = 0; ct < 4; ++ct)
#pragma unroll
        for (int ks = 0; ks < 2; ++ks)
            bf[ct][ks].q = Wb4[(ct * 2 + ks) * 64 + lane];

    int rbase0 = blockIdx.x * 128 + wave * 32;
    f32x4 acc[2][4] = {};
#pragma unroll
    for (int sub = 0; sub < 2; ++sub) {
        int row = min(rbase0 + sub * 16 + l15, n - 1);
        ABFrag a[2];
        if (BFIN) {
            const uint4* X4 = (const uint4*)Xv;
#pragma unroll
            for (int ks = 0; ks < 2; ++ks)
                a[ks].q = X4[(size_t)row * 8 + ks * 4 + grp];
        } else {
            const float4* X4 = (const float4*)Xv;
#pragma unroll
            for (int ks = 0; ks < 2; ++ks) {
                float4 f0 = X4[(size_t)row * 16 + ks * 8 + grp * 2];
                float4 f1 = X4[(size_t)row * 16 + ks * 8 + grp * 2 + 1];
                a[ks].u[0] = packbf16(f0.x, f0.y);
                a[ks].u[1] = packbf16(f0.z, f0.w);
                a[ks].u[2] = packbf16(f1.x, f1.y);
                a[ks].u[3] = packbf16(f1.z, f1.w);
            }
        }
#pragma unroll
        for (int ct = 0; ct < 4; ++ct) {
            acc[sub][ct] = __builtin_amdgcn_mfma_f32_16x16x32_bf16(a[0].v, bf[ct][0].v,
                                                                   acc[sub][ct], 0, 0, 0);
            acc[sub][ct] = __builtin_amdgcn_mfma_f32_16x16x32_bf16(a[1].v, bf[ct][1].v,
                                                                   acc[sub][ct], 0, 0, 0);
        }
    }
#pragma unroll
    for (int sub = 0; sub < 2; ++sub) {
        int rb = rbase0 + sub * 16;
#pragma unroll
        for (int r = 0; r < 4; ++r) {
            int row = rb + grp * 4 + r;
            float dd = dinv[min(row, n - 1)];
#pragma unroll
            for (int ct = 0; ct < 4; ++ct) {
                float v = acc[sub][ct][r] * dd;
                float w = __shfl_xor(v, 1);
                if (!(lane & 1) && row < n)
                    Y[(size_t)row * 32 + ct * 8 + (l15 >> 1)] = packbf16(v, w);
            }
        }
    }
}

// ---------------- fused aggregate: wide uint4 gathers, 4 edges per instruction ----------------
// one node per HALF-wave; lane = (edge-group grp 0..3) x (row-quarter sub 0..7).
// batch-16 edges = 4 gather instructions; shfl-reduce groups at end.
template <int DOPOOL>
__global__ __launch_bounds__(256) void k_aggregate(const uint32* __restrict__ h,
                                                   const int* __restrict__ csrs,
                                                   const int* __restrict__ rowptr,
                                                   const float* __restrict__ dinv,
                                                   const float* __restrict__ b,
                                                   const int* __restrict__ batch,
                                                   uint32* __restrict__ hout,
                                                   float* __restrict__ pooled, int n) {
    __shared__ float red[8][64];
    __shared__ int sg[8];
    int tid = threadIdx.x;
    int wave = tid >> 6;
    int lane = tid & 63;
    int half = lane >> 5;
    int hl = lane & 31;
    int grp = hl >> 3;   // edge within gather instruction (0..3)
    int sub = hl & 7;    // uint4 index within 128B row (0..7)
    int slot = wave * 2 + half;
    int node = blockIdx.x * 8 + slot;
    bool active = node < n;
    const uint4* h4 = (const uint4*)h;
    float acc[8] = {};
    float o[8] = {};
    if (active) {
        int r0 = rowptr[node];
        int r1 = rowptr[node + 1];
        int m = r1 - 1;
        for (int e = r0; e < r1; e += 16) {
            int eA = e + grp, eB = e + 4 + grp, eC = e + 8 + grp, eD = e + 12 + grp;
            int sA = csrs[min(eA, m)];
            int sB = csrs[min(eB, m)];
            int sC = csrs[min(eC, m)];
            int sD = csrs[min(eD, m)];
            uint4 gA = h4[(size_t)sA * 8 + sub];
            uint4 gB = h4[(size_t)sB * 8 + sub];
            uint4 gC = h4[(size_t)sC * 8 + sub];
            uint4 gD = h4[(size_t)sD * 8 + sub];
            if (eA > m) { gA.x = gA.y = gA.z = gA.w = 0u; }
            if (eB > m) { gB.x = gB.y = gB.z = gB.w = 0u; }
            if (eC > m) { gC.x = gC.y = gC.z = gC.w = 0u; }
            if (eD > m) { gD.x = gD.y = gD.z = gD.w = 0u; }
            acc[0] += bf16lo(gA.x) + bf16lo(gB.x) + bf16lo(gC.x) + bf16lo(gD.x);
            acc[1] += bf16hi(gA.x) + bf16hi(gB.x) + bf16hi(gC.x) + bf16hi(gD.x);
            acc[2] += bf16lo(gA.y) + bf16lo(gB.y) + bf16lo(gC.y) + bf16lo(gD.y);
            acc[3] += bf16hi(gA.y) + bf16hi(gB.y) + bf16hi(gC.y) + bf16hi(gD.y);
            acc[4] += bf16lo(gA.z) + bf16lo(gB.z) + bf16lo(gC.z) + bf16lo(gD.z);
            acc[5] += bf16hi(gA.z) + bf16hi(gB.z) + bf16hi(gC.z) + bf16hi(gD.z);
            acc[6] += bf16lo(gA.w) + bf16lo(gB.w) + bf16lo(gC.w) + bf16lo(gD.w);
            acc[7] += bf16hi(gA.w) + bf16hi(gB.w) + bf16hi(gC.w) + bf16hi(gD.w);
        }
        // reduce the 4 edge-groups (lanes sub, sub+8, sub+16, sub+24 of this half)
#pragma unroll
        for (int c = 0; c < 8; ++c) {
            acc[c] += __shfl_xor(acc[c], 8);
            acc[c] += __shfl_xor(acc[c], 16);
        }
        // self term + epilogue on lanes grp==0 (hl = sub = 0..7)
        uint4 sv = h4[(size_t)node * 8 + sub];
        float dd = dinv[node];
        if (grp == 0) {
            float s0 = bf16lo(sv.x), s1 = bf16hi(sv.x);
            float s2 = bf16lo(sv.y), s3 = bf16hi(sv.y);
            float s4 = bf16lo(sv.z), s5 = bf16hi(sv.z);
            float s6 = bf16lo(sv.w), s7 = bf16hi(sv.w);
            o[0] = (acc[0] + s0) * dd + b[hl * 8 + 0];
            o[1] = (acc[1] + s1) * dd + b[hl * 8 + 1];
            o[2] = (acc[2] + s2) * dd + b[hl * 8 + 2];
            o[3] = (acc[3] + s3) * dd + b[hl * 8 + 3];
            o[4] = (acc[4] + s4) * dd + b[hl * 8 + 4];
            o[5] = (acc[5] + s5) * dd + b[hl * 8 + 5];
            o[6] = (acc[6] + s6) * dd + b[hl * 8 + 6];
            o[7] = (acc[7] + s7) * dd + b[hl * 8 + 7];
#pragma unroll
            for (int c = 0; c < 8; ++c) o[c] = o[c] > 0.f ? o[c] : 0.f;
            if (!DOPOOL) {
                uint4 u;
                u.x = packbf16(o[0], o[1]);
                u.y = packbf16(o[2], o[3]);
                u.z = packbf16(o[4], o[5]);
                u.w = packbf16(o[6], o[7]);
                ((uint4*)hout)[(size_t)node * 8 + hl] = u;
            }
        }
    }
    if (DOPOOL) {
        if (grp == 0) {
#pragma unroll
            for (int c = 0; c < 8; ++c)
                red[slot][hl * 8 + c] = active ? o[c] : 0.f;
        }
        if (hl == 0) sg[slot] = active ? batch[node] : -1;
        __syncthreads();
        if (wave == 0) {
            float s = red[0][lane];
            int gcur = sg[0];
            for (int w = 1; w < 8; ++w) {
                int gw = sg[w];
                if (gw < 0) break;
                if (gw == gcur) {
                    s += red[w][lane];
                } else {
                    if (gcur >= 0) atomicAdd(&pooled[gcur * H + lane], s);
                    s = red[w][lane];
                    gcur = gw;
                }
            }
            if (gcur >= 0) atomicAdd(&pooled[gcur * H + lane], s);
        }
    }
}

// ---------------- final linear ----------------
__global__ void k_final(const float* __restrict__ pooled, const float* __restrict__ gf,
                        const float* __restrict__ Wlin, const float* __restrict__ blin,
                        float* __restrict__ out) {
    int t = threadIdx.x;
    if (t >= G * OUT) return;
    int g = t >> 1, o = t & 1;
    float acc = blin[o];
#pragma unroll
    for (int j = 0; j < 64; ++j) acc += pooled[g * H + j] * Wlin[j * OUT + o];
    acc += gf[g] * Wlin[64 * OUT + o];
    out[g * OUT + o] = acc;
}

extern "C" void kernel_launch(void* const* d_in, const int* in_sizes, int n_in,
                              void* d_out, int out_size, void* d_ws, size_t ws_size,
                              hipStream_t stream) {
    const float* x          = (const float*)d_in[0];
    const int*   edge_index = (const int*)d_in[1];
    const int*   batch      = (const int*)d_in[2];
    const float* gf         = (const float*)d_in[3];
    const float* W1         = (const float*)d_in[4];
    const float* b1         = (const float*)d_in[5];
    const float* W2         = (const float*)d_in[6];
    const float* b2         = (const float*)d_in[7];
    const float* Wlin       = (const float*)d_in[8];
    const float* blin       = (const float*)d_in[9];
    float* out = (float*)d_out;

    const int N = in_sizes[0] / H;
    const int E = in_sizes[1] / 2;
    const int* src = edge_index;
    const int* dst = edge_index + E;
    const int NBUK = (N + (1 << BSHIFT) - 1) >> BSHIFT;  // 98 for N=100k (<=MAXBUK)

    // workspace layout
    float* ws = (float*)d_ws;
    float* dinv   = ws;                         // N
    uint32* bufA  = (uint32*)(dinv + N);        // N*32 uints (bf16 packed), 16B-aligned
    uint32* bufB  = bufA + (size_t)N * 32;      // N*32 uints
    float* pooled = (float*)(bufB + (size_t)N * 32);  // G*H
    int*   rowptr = (int*)(pooled + G * H);     // N+1
    int*   bcnt   = rowptr + (N + 1);           // MAXBUK
    int*   bbase  = bcnt + MAXBUK;              // MAXBUK+1
    int*   bcur   = bbase + (MAXBUK + 1);       // MAXBUK
    int*   done   = bcur + MAXBUK;              // 1
    size_t off = (size_t)(done + 1 - (int*)d_ws);
    off = (off + 3) & ~(size_t)3;               // 16B align
    uint32* Wb   = (uint32*)d_ws + off;         // 2 * 2048 uints
    int*   csrs  = (int*)(Wb + 2 * 2048);       // E ints
    uint32* inter = (uint32*)(csrs + E);        // E uints (packed ln<<17|src)

    const int T = 256;

    // setup + CSR build (bscan fused into bhist's last block)
    k_setup<<<3, T, 0, stream>>>(W1, W2, Wb, pooled, bcnt, done);
    k_bhist<<<256, T, 0, stream>>>(dst, bcnt, bbase, bcur, done, E, NBUK);
    k_bscatter<<<128, T, 0, stream>>>(src, dst, bcur, inter, E);
    k_build<<<NBUK, T, 0, stream>>>(inter, bbase, rowptr, dinv, csrs, N, NBUK);

    const int NBG = (N + 127) / 128;

    // layer 1
    k_gemm_mfma<0><<<NBG, T, 0, stream>>>(x, Wb, dinv, bufA, N);
    k_aggregate<0><<<(N + 7) / 8, T, 0, stream>>>(bufA, csrs, rowptr, dinv, b1, batch,
                                                  bufB, pooled, N);

    // layer 2 + fused pool
    k_gemm_mfma<1><<<NBG, T, 0, stream>>>(bufB, Wb + 2048, dinv, bufA, N);
    k_aggregate<1><<<(N + 7) / 8, T, 0, stream>>>(bufA, csrs, rowptr, dinv, b2, batch,
                                                  nullptr, pooled, N);

    // head
    k_final<<<1, 128, 0, stream>>>(pooled, gf, Wlin, blin, out);
}